// Round 9
// baseline (187.951 us; speedup 1.0000x reference)
//
#include <hip/hip_runtime.h>
#include <hip/hip_bf16.h>

typedef __bf16 bf16x8 __attribute__((ext_vector_type(8)));
typedef float  f32x4  __attribute__((ext_vector_type(4)));
typedef unsigned short u16;

__device__ __forceinline__ u16 f2bf(float f) {
    __bf16 h = (__bf16)f;
    return __builtin_bit_cast(u16, h);
}

__device__ __forceinline__ f32x4 mfma16(bf16x8 a, bf16x8 b, f32x4 c) {
    return __builtin_amdgcn_mfma_f32_16x16x32_bf16(a, b, c, 0, 0, 0);
}

// async global->LDS, 16B per lane. LDS dest = wave-uniform base + lane*16.
__device__ __forceinline__ void gload16(const u16* g, u16* l) {
    __builtin_amdgcn_global_load_lds(
        (const __attribute__((address_space(1))) void*)g,
        (__attribute__((address_space(3))) void*)l, 16, 0, 0);
}

// ---------------------------------------------------------------------------
// cvtW: Wq,Wk,Wv,Wo (1M elems each) fp32 -> bf16 concatenated.
// ---------------------------------------------------------------------------
__global__ __launch_bounds__(256) void cvtW(const float* __restrict__ W0,
                                            const float* __restrict__ W1,
                                            const float* __restrict__ W2,
                                            const float* __restrict__ W3,
                                            u16* __restrict__ dst) {
    const int t     = blockIdx.x * 256 + threadIdx.x;   // 0..512K-1
    const int which = t >> 17;
    const int off   = (t & 0x1FFFF) * 8;
    const float* s  = (which == 0) ? W0 : (which == 1) ? W1 : (which == 2) ? W2 : W3;
    float4 f0 = *(const float4*)(s + off);
    float4 f1 = *(const float4*)(s + off + 4);
    bf16x8 u;
    u[0] = (__bf16)f0.x; u[1] = (__bf16)f0.y; u[2] = (__bf16)f0.z; u[3] = (__bf16)f0.w;
    u[4] = (__bf16)f1.x; u[5] = (__bf16)f1.y; u[6] = (__bf16)f1.z; u[7] = (__bf16)f1.w;
    *(bf16x8*)(dst + ((size_t)which << 20) + off) = u;
}

// ---------------------------------------------------------------------------
// Merged Q/K/V GEMM. 128x128 tile, BK=64, 4 waves, 768 blocks.
// Frag-major LDS (conflict-free both sides), double-buffered, 2-phase
// overlap: issue stage(t+1) -> compute(t) -> write A(t+1) -> barrier.
// A fp32 reg-staged+cvt; B bf16 via global_load_lds.
// chunk c: frag=c>>6, l=c&63, row=(frag&7)*16+(l&15), kof=(frag>>3)*32+(l>>4)*8
// dest byte = c*16 (wave-contiguous 1KB for both DMA and ds_write/ds_read).
// ---------------------------------------------------------------------------
__global__ __launch_bounds__(256) void gemm_qkv(const float* __restrict__ q,
                                                const float* __restrict__ k,
                                                const float* __restrict__ v,
                                                const u16* __restrict__ Wb,
                                                u16* __restrict__ Qp,
                                                u16* __restrict__ Kp,
                                                u16* __restrict__ Vt) {
    constexpr int K = 1024, N = 1024;
    __shared__ __align__(16) u16 As[2][8192];   // 2 x 16 KB
    __shared__ __align__(16) u16 Bs[2][8192];   // 2 x 16 KB

    const int tid  = threadIdx.x;
    const int lane = tid & 63;
    const int w    = tid >> 6;
    const int wr = w >> 1, wc = w & 1;
    const int wg    = (blockIdx.x & 7) * 96 + (blockIdx.x >> 3);  // XCD swizzle
    const int which = wg >> 8;
    const int inner = wg & 255;
    const int m0 = (inner >> 3) * 128, n0 = (inner & 7) * 128;
    const int colg = lane & 15, rowg = lane >> 4;

    const float* A = (which == 0) ? q : (which == 1) ? k : v;
    const u16*   W = Wb + ((size_t)which << 20);

    size_t aoff[4], boff[4];
    int dofs[4];
#pragma unroll
    for (int i = 0; i < 4; ++i) {
        const int c = i * 256 + tid;
        const int g = c >> 6, l = c & 63;
        const int row = (g & 7) * 16 + (l & 15);
        const int kof = (g >> 3) * 32 + (l >> 4) * 8;
        aoff[i] = (size_t)(m0 + row) * K + kof;
        boff[i] = (size_t)(n0 + row) * K + kof;
        dofs[i] = c * 8;   // u16 units
    }

    f32x4 acc[4][4];
#pragma unroll
    for (int i = 0; i < 4; ++i)
#pragma unroll
        for (int j = 0; j < 4; ++j) acc[i][j] = (f32x4){0.f, 0.f, 0.f, 0.f};

    float4 ar0[4], ar1[4];
    // --- prologue: tile 0 ---
#pragma unroll
    for (int i = 0; i < 4; ++i) {
        ar0[i] = *(const float4*)(A + aoff[i]);
        ar1[i] = *(const float4*)(A + aoff[i] + 4);
        gload16(W + boff[i], &Bs[0][dofs[i]]);
    }
#pragma unroll
    for (int i = 0; i < 4; ++i) {
        bf16x8 u;
        u[0] = (__bf16)ar0[i].x; u[1] = (__bf16)ar0[i].y;
        u[2] = (__bf16)ar0[i].z; u[3] = (__bf16)ar0[i].w;
        u[4] = (__bf16)ar1[i].x; u[5] = (__bf16)ar1[i].y;
        u[6] = (__bf16)ar1[i].z; u[7] = (__bf16)ar1[i].w;
        *(bf16x8*)(&As[0][dofs[i]]) = u;
    }
    __syncthreads();   // B(0) drained, A(0) visible

    int cur = 0;
    for (int t = 0; t < 16; ++t) {
        // issue stage(t+1): flies under compute(t)
        if (t < 15) {
            const int kk = (t + 1) * 64;
#pragma unroll
            for (int i = 0; i < 4; ++i) {
                ar0[i] = *(const float4*)(A + aoff[i] + kk);
                ar1[i] = *(const float4*)(A + aoff[i] + kk + 4);
                gload16(W + boff[i] + kk, &Bs[cur ^ 1][dofs[i]]);
            }
        }
        // compute(t)
#pragma unroll
        for (int ks = 0; ks < 2; ++ks) {
            bf16x8 af[4], bfr[4];
#pragma unroll
            for (int mi = 0; mi < 4; ++mi)
                af[mi] = *(const bf16x8*)(&As[cur][(ks * 8 + wr * 4 + mi) * 512 + lane * 8]);
#pragma unroll
            for (int ni = 0; ni < 4; ++ni)
                bfr[ni] = *(const bf16x8*)(&Bs[cur][(ks * 8 + wc * 4 + ni) * 512 + lane * 8]);
#pragma unroll
            for (int mi = 0; mi < 4; ++mi)
#pragma unroll
                for (int ni = 0; ni < 4; ++ni)
                    acc[mi][ni] = mfma16(af[mi], bfr[ni], acc[mi][ni]);
        }
        // cvt + write A(t+1) (loads completed during compute)
        if (t < 15) {
#pragma unroll
            for (int i = 0; i < 4; ++i) {
                bf16x8 u;
                u[0] = (__bf16)ar0[i].x; u[1] = (__bf16)ar0[i].y;
                u[2] = (__bf16)ar0[i].z; u[3] = (__bf16)ar0[i].w;
                u[4] = (__bf16)ar1[i].x; u[5] = (__bf16)ar1[i].y;
                u[6] = (__bf16)ar1[i].z; u[7] = (__bf16)ar1[i].w;
                *(bf16x8*)(&As[cur ^ 1][dofs[i]]) = u;
            }
        }
        __syncthreads();   // drains B(t+1) DMA (covered by compute), orders A writes
        cur ^= 1;
    }

    u16* Crm = (which == 0) ? Qp : Kp;
#pragma unroll
    for (int mi = 0; mi < 4; ++mi) {
#pragma unroll
        for (int ni = 0; ni < 4; ++ni) {
#pragma unroll
            for (int r = 0; r < 4; ++r) {
                const int row = m0 + wr * 64 + mi * 16 + rowg * 4 + r;
                const int col = n0 + wc * 64 + ni * 16 + colg;
                const float vv = acc[mi][ni][r];
                if (which < 2) {
                    Crm[(size_t)row * N + col] = f2bf(vv);
                } else {
                    const int b = row >> 11, tt = row & 2047;
                    const int h = col >> 6,  d = col & 63;
                    Vt[((size_t)((b * 16 + h) * 64 + d) << 11) + tt] = f2bf(vv);
                }
            }
        }
    }
}

// ---------------------------------------------------------------------------
// Output GEMM: 128x128/BK=64, dbuf 2-phase overlap, all-bf16 DMA, fp32 out.
// 256 blocks.
// ---------------------------------------------------------------------------
__global__ __launch_bounds__(256) void gemm_out(const u16* __restrict__ Ap,
                                                const u16* __restrict__ W,
                                                float* __restrict__ Cp) {
    constexpr int K = 1024, N = 1024;
    __shared__ __align__(16) u16 As[2][8192];
    __shared__ __align__(16) u16 Bs[2][8192];

    const int tid  = threadIdx.x;
    const int lane = tid & 63;
    const int w    = tid >> 6;
    const int wr = w >> 1, wc = w & 1;
    const int wg = (blockIdx.x & 7) * 32 + (blockIdx.x >> 3);  // XCD swizzle
    const int m0 = (wg >> 3) * 128, n0 = (wg & 7) * 128;
    const int colg = lane & 15, rowg = lane >> 4;

    size_t aoff[4], boff[4];
    int dofs[4];
#pragma unroll
    for (int i = 0; i < 4; ++i) {
        const int c = i * 256 + tid;
        const int g = c >> 6, l = c & 63;
        const int row = (g & 7) * 16 + (l & 15);
        const int kof = (g >> 3) * 32 + (l >> 4) * 8;
        aoff[i] = (size_t)(m0 + row) * K + kof;
        boff[i] = (size_t)(n0 + row) * K + kof;
        dofs[i] = c * 8;
    }

    f32x4 acc[4][4];
#pragma unroll
    for (int i = 0; i < 4; ++i)
#pragma unroll
        for (int j = 0; j < 4; ++j) acc[i][j] = (f32x4){0.f, 0.f, 0.f, 0.f};

    // prologue: tile 0 DMA
#pragma unroll
    for (int i = 0; i < 4; ++i) {
        gload16(Ap + aoff[i], &As[0][dofs[i]]);
        gload16(W + boff[i], &Bs[0][dofs[i]]);
    }
    __syncthreads();

    int cur = 0;
    for (int t = 0; t < 16; ++t) {
        if (t < 15) {
            const int kk = (t + 1) * 64;
#pragma unroll
            for (int i = 0; i < 4; ++i) {
                gload16(Ap + aoff[i] + kk, &As[cur ^ 1][dofs[i]]);
                gload16(W + boff[i] + kk, &Bs[cur ^ 1][dofs[i]]);
            }
        }
#pragma unroll
        for (int ks = 0; ks < 2; ++ks) {
            bf16x8 af[4], bfr[4];
#pragma unroll
            for (int mi = 0; mi < 4; ++mi)
                af[mi] = *(const bf16x8*)(&As[cur][(ks * 8 + wr * 4 + mi) * 512 + lane * 8]);
#pragma unroll
            for (int ni = 0; ni < 4; ++ni)
                bfr[ni] = *(const bf16x8*)(&Bs[cur][(ks * 8 + wc * 4 + ni) * 512 + lane * 8]);
#pragma unroll
            for (int mi = 0; mi < 4; ++mi)
#pragma unroll
                for (int ni = 0; ni < 4; ++ni)
                    acc[mi][ni] = mfma16(af[mi], bfr[ni], acc[mi][ni]);
        }
        __syncthreads();
        cur ^= 1;
    }

#pragma unroll
    for (int mi = 0; mi < 4; ++mi)
#pragma unroll
        for (int ni = 0; ni < 4; ++ni)
#pragma unroll
            for (int r = 0; r < 4; ++r) {
                const int row = m0 + wr * 64 + mi * 16 + rowg * 4 + r;
                const int col = n0 + wc * 64 + ni * 16 + colg;
                Cp[(size_t)row * N + col] = acc[mi][ni][r];
            }
}

// ---------------------------------------------------------------------------
// Flash attention v3 (unchanged): 4-wave blocks, block-staged K/V in swizzled
// LDS, swapped QK^T (lane-local softmax), defer-rescale.
// ---------------------------------------------------------------------------
constexpr float CEXP = 0.18033688011112042f;  // 0.125 * log2(e)

__global__ __launch_bounds__(256) void attn_causal(const u16* __restrict__ Qp,
                                                   const u16* __restrict__ Kp,
                                                   const u16* __restrict__ Vt,
                                                   u16* __restrict__ concat) {
    constexpr int T = 2048, C = 1024;
    __shared__ __align__(16) u16 Ks[128 * 64];
    __shared__ __align__(16) u16 Vs[64 * 128];
    __shared__ __align__(16) u16 Pl[4][2048];

    const int tid  = threadIdx.x;
    const int lane = tid & 63;
    const int w    = tid >> 6;
    const int colg = lane & 15, rowg = lane >> 4;

    const int idx = blockIdx.x;
    const int xcd = idx & 7;
    const int i1  = idx >> 3;
    const int bh  = xcd * 4 + (i1 & 3);
    const int qg  = 31 - (i1 >> 2);
    const int b = bh >> 4, h = bh & 15;

    const int q0 = (qg * 4 + w) * 16;
    const int nt    = (q0 + 143) >> 7;
    const int ktmax = ((qg * 4 + 3) * 16 + 143) >> 7;

    const char* Kg = (const char*)(Kp + (size_t)(b * T) * C + h * 64);
    const char* Vg = (const char*)(Vt + ((size_t)(b * 16 + h) * 64) * T);
    char* Ksb = (char*)Ks;
    char* Vsb = (char*)Vs;
    char* Pw  = (char*)&Pl[w][0];

    const u16* Qb = Qp + (size_t)(b * T + q0 + colg) * C + h * 64;
    const bf16x8 qf0 = *(const bf16x8*)(Qb + rowg * 8);
    const bf16x8 qf1 = *(const bf16x8*)(Qb + 32 + rowg * 8);

    float mm = -1e30f, ll = 0.f;
    f32x4 O[4];
#pragma unroll
    for (int g = 0; g < 4; ++g) O[g] = (f32x4){0.f, 0.f, 0.f, 0.f};

    const int sw = (colg & 7) << 4;

    for (int kt = 0; kt < ktmax; ++kt) {
        const int kvb = kt * 128;
        uint4 kst[4], vst[4];
#pragma unroll
        for (int i2 = 0; i2 < 4; ++i2) {
            const int s  = i2 * 4096 + tid * 16;
            const int kv = s >> 7, ir = s & 127;
            kst[i2] = *(const uint4*)(Kg + (size_t)(kvb + kv) * 2048 + ir);
            const int d = s >> 8, irv = s & 255;
            vst[i2] = *(const uint4*)(Vg + (size_t)d * 4096 + (size_t)kvb * 2 + irv);
        }
#pragma unroll
        for (int i2 = 0; i2 < 4; ++i2) {
            const int s  = i2 * 4096 + tid * 16;
            const int kv = s >> 7;
            *(uint4*)(Ksb + (s ^ ((kv & 7) << 4))) = kst[i2];
            const int d = s >> 8;
            *(uint4*)(Vsb + (s ^ ((d & 7) << 4))) = vst[i2];
        }
        __syncthreads();

        if (kt < nt) {
            float pr[8][4];
#pragma unroll
            for (int sub = 0; sub < 8; ++sub) {
                const int kb = (sub * 16 + colg) * 128 + rowg * 16;
                bf16x8 kf0 = *(const bf16x8*)(Ksb + (kb ^ sw));
                bf16x8 kf1 = *(const bf16x8*)(Ksb + ((kb + 64) ^ sw));
                f32x4 t = (f32x4){0.f, 0.f, 0.f, 0.f};
                t = mfma16(kf0, qf0, t);
                t = mfma16(kf1, qf1, t);
#pragma unroll
                for (int r = 0; r < 4; ++r) pr[sub][r] = t[r];
            }
            if (kvb + 127 > q0) {
#pragma unroll
                for (int sub = 0; sub < 8; ++sub)
#pragma unroll
                    for (int r = 0; r < 4; ++r)
                        if (kvb + sub * 16 + rowg * 4 + r > q0 + colg) pr[sub][r] = -1e30f;
            }
            float mx[8];
#pragma unroll
            for (int sub = 0; sub < 8; ++sub)
                mx[sub] = fmaxf(fmaxf(pr[sub][0], pr[sub][1]), fmaxf(pr[sub][2], pr[sub][3]));
            float pm = fmaxf(fmaxf(fmaxf(mx[0], mx[1]), fmaxf(mx[2], mx[3])),
                             fmaxf(fmaxf(mx[4], mx[5]), fmaxf(mx[6], mx[7])));
            pm = fmaxf(pm, __shfl_xor(pm, 16, 64));
            pm = fmaxf(pm, __shfl_xor(pm, 32, 64));
            if (__any(pm > mm + 40.f)) {
                const float mn = fmaxf(mm, pm);
                const float sc = __builtin_amdgcn_exp2f((mm - mn) * CEXP);
                mm = mn;
                ll *= sc;
#pragma unroll
                for (int r = 0; r < 4; ++r) {
                    const float scr = __shfl(sc, (lane & 48) + rowg * 4 + r, 64);
#pragma unroll
                    for (int g = 0; g < 4; ++g) O[g][r] *= scr;
                }
            }
            float rs = 0.f;
#pragma unroll
            for (int sub = 0; sub < 8; ++sub) {
                const float e0 = __builtin_amdgcn_exp2f((pr[sub][0] - mm) * CEXP);
                const float e1 = __builtin_amdgcn_exp2f((pr[sub][1] - mm) * CEXP);
                const float e2 = __builtin_amdgcn_exp2f((pr[sub][2] - mm) * CEXP);
                const float e3 = __builtin_amdgcn_exp2f((pr[sub][3] - mm) * CEXP);
                pr[sub][0] = e0; pr[sub][1] = e1; pr[sub][2] = e2; pr[sub][3] = e3;
                rs += (e0 + e1) + (e2 + e3);
            }
            rs += __shfl_xor(rs, 16, 64);
            rs += __shfl_xor(rs, 32, 64);
            ll += rs;
#pragma unroll
            for (int sub = 0; sub < 8; ++sub) {
                uint2 pk;
                pk.x = (unsigned)f2bf(pr[sub][0]) | ((unsigned)f2bf(pr[sub][1]) << 16);
                pk.y = (unsigned)f2bf(pr[sub][2]) | ((unsigned)f2bf(pr[sub][3]) << 16);
                const int wb = (colg * 256 + sub * 32 + rowg * 8) ^ sw;
                *(uint2*)(Pw + wb) = pk;
            }
            bf16x8 pf[4];
#pragma unroll
            for (int kc = 0; kc < 4; ++kc)
                pf[kc] = *(const bf16x8*)(Pw + ((colg * 256 + kc * 64 + rowg * 16) ^ sw));
#pragma unroll
            for (int g = 0; g < 4; ++g) {
                const int vb0 = (g * 16 + colg) * 256 + rowg * 16;
#pragma unroll
                for (int kc = 0; kc < 4; ++kc) {
                    bf16x8 vf = *(const bf16x8*)(Vsb + ((vb0 + kc * 64) ^ sw));
                    O[g] = mfma16(pf[kc], vf, O[g]);
                }
            }
        }
        __syncthreads();
    }

#pragma unroll
    for (int r = 0; r < 4; ++r) {
        const float lr = __shfl(ll, (lane & 48) + rowg * 4 + r, 64);
        const float rc = 1.f / lr;
        const size_t base = (size_t)(b * T + q0 + rowg * 4 + r) * C + h * 64;
#pragma unroll
        for (int g = 0; g < 4; ++g)
            concat[base + g * 16 + colg] = f2bf(O[g][r] * rc);
    }
}

// ---------------------------------------------------------------------------
extern "C" void kernel_launch(void* const* d_in, const int* in_sizes, int n_in,
                              void* d_out, int out_size, void* d_ws, size_t ws_size,
                              hipStream_t stream) {
    const float* q  = (const float*)d_in[0];
    const float* k  = (const float*)d_in[1];
    const float* v  = (const float*)d_in[2];
    const float* Wq = (const float*)d_in[3];
    const float* Wk = (const float*)d_in[4];
    const float* Wv = (const float*)d_in[5];
    const float* Wo = (const float*)d_in[6];
    float* out = (float*)d_out;

    constexpr size_t NELEM = (size_t)4096 * 1024;  // 4M
    constexpr size_t WSZ   = (size_t)1 << 20;      // 1M
    u16* Wbf = (u16*)d_ws;          // bf16 weights    4M
    u16* Qp  = Wbf + 4 * WSZ;       // proj Q          4M
    u16* Kp  = Qp + NELEM;          // proj K          4M
    u16* Vt  = Kp + NELEM;          // proj V (transp) 4M
    u16* Cc  = Vt + NELEM;          // attn concat     4M

    cvtW<<<2048, 256, 0, stream>>>(Wq, Wk, Wv, Wo, Wbf);

    gemm_qkv<<<768, 256, 0, stream>>>(q, k, v, Wbf, Qp, Kp, Vt);

    attn_causal<<<1024, 256, 0, stream>>>(Qp, Kp, Vt, Cc);

    gemm_out<<<256, 256, 0, stream>>>(Cc, Wbf + 3 * WSZ, out);
}

// Round 10
// 180.259 us; speedup vs baseline: 1.0427x; 1.0427x over previous
//
#include <hip/hip_runtime.h>
#include <hip/hip_bf16.h>

typedef __bf16 bf16x8 __attribute__((ext_vector_type(8)));
typedef float  f32x4  __attribute__((ext_vector_type(4)));
typedef unsigned short u16;

__device__ __forceinline__ u16 f2bf(float f) {
    __bf16 h = (__bf16)f;
    return __builtin_bit_cast(u16, h);
}

__device__ __forceinline__ f32x4 mfma16(bf16x8 a, bf16x8 b, f32x4 c) {
    return __builtin_amdgcn_mfma_f32_16x16x32_bf16(a, b, c, 0, 0, 0);
}

// ---------------------------------------------------------------------------
// cvtW: Wq,Wk,Wv,Wo (1M elems each) fp32 -> bf16 concatenated.
// ---------------------------------------------------------------------------
__global__ __launch_bounds__(256) void cvtW(const float* __restrict__ W0,
                                            const float* __restrict__ W1,
                                            const float* __restrict__ W2,
                                            const float* __restrict__ W3,
                                            u16* __restrict__ dst) {
    const int t     = blockIdx.x * 256 + threadIdx.x;   // 0..512K-1
    const int which = t >> 17;
    const int off   = (t & 0x1FFFF) * 8;
    const float* s  = (which == 0) ? W0 : (which == 1) ? W1 : (which == 2) ? W2 : W3;
    float4 f0 = *(const float4*)(s + off);
    float4 f1 = *(const float4*)(s + off + 4);
    bf16x8 u;
    u[0] = (__bf16)f0.x; u[1] = (__bf16)f0.y; u[2] = (__bf16)f0.z; u[3] = (__bf16)f0.w;
    u[4] = (__bf16)f1.x; u[5] = (__bf16)f1.y; u[6] = (__bf16)f1.z; u[7] = (__bf16)f1.w;
    *(bf16x8*)(dst + ((size_t)which << 20) + off) = u;
}

// ---------------------------------------------------------------------------
// Merged Q/K/V GEMM. 128x128 tile, BK=32, 4 waves, 768 blocks.
// r6 structure (reg-staged, single-buffered, 2 barriers, 16KB LDS) with
// FRAG-MAJOR LDS layout: fragment f (16 rows x 32k) lives at f*1KB, lane's
// 16B at +lane*16. Staging writes and fragment reads are both wave-linear
// 1KB runs => zero bank conflicts on both sides. The row/k permutation is
// folded into the global source addresses (full 128B lines still covered
// in-wave => no over-fetch).
// chunk c (0..511): f=c>>6, l=c&63 -> row=f*16+(l&15), kof=(l>>4)*8.
// ---------------------------------------------------------------------------
__global__ __launch_bounds__(256) void gemm_qkv(const float* __restrict__ q,
                                                const float* __restrict__ k,
                                                const float* __restrict__ v,
                                                const u16* __restrict__ Wb,
                                                u16* __restrict__ Qp,
                                                u16* __restrict__ Kp,
                                                u16* __restrict__ Vt) {
    constexpr int K = 1024, N = 1024;
    __shared__ __align__(16) u16 As[4096];   // 8 KB = 8 frags x 1KB
    __shared__ __align__(16) u16 Bs[4096];   // 8 KB

    const int tid  = threadIdx.x;
    const int lane = tid & 63;
    const int w    = tid >> 6;
    const int wr = w >> 1, wc = w & 1;
    const int wg    = (blockIdx.x & 7) * 96 + (blockIdx.x >> 3);  // XCD swizzle
    const int which = wg >> 8;
    const int inner = wg & 255;
    const int m0 = (inner >> 3) * 128, n0 = (inner & 7) * 128;
    const int colg = lane & 15, rowg = lane >> 4;

    const float* A = (which == 0) ? q : (which == 1) ? k : v;
    const u16*   W = Wb + ((size_t)which << 20);

    size_t aoff[2], boff[2];
    int dofs[2];
#pragma unroll
    for (int i = 0; i < 2; ++i) {
        const int c = i * 256 + tid;
        const int f = c >> 6, l = c & 63;
        const int row = f * 16 + (l & 15);
        const int kof = (l >> 4) * 8;
        aoff[i] = (size_t)(m0 + row) * K + kof;
        boff[i] = (size_t)(n0 + row) * K + kof;
        dofs[i] = c * 8;   // u16 units
    }

    f32x4 acc[4][4];
#pragma unroll
    for (int i = 0; i < 4; ++i)
#pragma unroll
        for (int j = 0; j < 4; ++j) acc[i][j] = (f32x4){0.f, 0.f, 0.f, 0.f};

    for (int t = 0; t < 32; ++t) {
        const int kk = t * 32;
        float4 a0[2], a1[2];
        uint4  bv[2];
#pragma unroll
        for (int i = 0; i < 2; ++i) {
            a0[i] = *(const float4*)(A + aoff[i] + kk);
            a1[i] = *(const float4*)(A + aoff[i] + kk + 4);
            bv[i] = *(const uint4*)(W + boff[i] + kk);
        }
#pragma unroll
        for (int i = 0; i < 2; ++i) {
            bf16x8 u;
            u[0] = (__bf16)a0[i].x; u[1] = (__bf16)a0[i].y;
            u[2] = (__bf16)a0[i].z; u[3] = (__bf16)a0[i].w;
            u[4] = (__bf16)a1[i].x; u[5] = (__bf16)a1[i].y;
            u[6] = (__bf16)a1[i].z; u[7] = (__bf16)a1[i].w;
            *(bf16x8*)(&As[dofs[i]]) = u;
            *(uint4*)(&Bs[dofs[i]]) = bv[i];
        }
        __syncthreads();

        bf16x8 af[4], bfr[4];
#pragma unroll
        for (int mi = 0; mi < 4; ++mi)
            af[mi] = *(const bf16x8*)(&As[(wr * 4 + mi) * 512 + lane * 8]);
#pragma unroll
        for (int ni = 0; ni < 4; ++ni)
            bfr[ni] = *(const bf16x8*)(&Bs[(wc * 4 + ni) * 512 + lane * 8]);
#pragma unroll
        for (int mi = 0; mi < 4; ++mi)
#pragma unroll
            for (int ni = 0; ni < 4; ++ni)
                acc[mi][ni] = mfma16(af[mi], bfr[ni], acc[mi][ni]);
        __syncthreads();
    }

    u16* Crm = (which == 0) ? Qp : Kp;
#pragma unroll
    for (int mi = 0; mi < 4; ++mi) {
#pragma unroll
        for (int ni = 0; ni < 4; ++ni) {
#pragma unroll
            for (int r = 0; r < 4; ++r) {
                const int row = m0 + wr * 64 + mi * 16 + rowg * 4 + r;
                const int col = n0 + wc * 64 + ni * 16 + colg;
                const float vv = acc[mi][ni][r];
                if (which < 2) {
                    Crm[(size_t)row * N + col] = f2bf(vv);
                } else {
                    const int b = row >> 11, tt = row & 2047;
                    const int h = col >> 6,  d = col & 63;
                    Vt[((size_t)((b * 16 + h) * 64 + d) << 11) + tt] = f2bf(vv);
                }
            }
        }
    }
}

// ---------------------------------------------------------------------------
// Output GEMM: same r6-style structure, all-bf16 reg-staged, frag-major LDS,
// 128x128/BK=32, 256 blocks, fp32 out.
// ---------------------------------------------------------------------------
__global__ __launch_bounds__(256) void gemm_out(const u16* __restrict__ Ap,
                                                const u16* __restrict__ W,
                                                float* __restrict__ Cp) {
    constexpr int K = 1024, N = 1024;
    __shared__ __align__(16) u16 As[4096];
    __shared__ __align__(16) u16 Bs[4096];

    const int tid  = threadIdx.x;
    const int lane = tid & 63;
    const int w    = tid >> 6;
    const int wr = w >> 1, wc = w & 1;
    const int wg = (blockIdx.x & 7) * 32 + (blockIdx.x >> 3);  // XCD swizzle
    const int m0 = (wg >> 3) * 128, n0 = (wg & 7) * 128;
    const int colg = lane & 15, rowg = lane >> 4;

    size_t aoff[2], boff[2];
    int dofs[2];
#pragma unroll
    for (int i = 0; i < 2; ++i) {
        const int c = i * 256 + tid;
        const int f = c >> 6, l = c & 63;
        const int row = f * 16 + (l & 15);
        const int kof = (l >> 4) * 8;
        aoff[i] = (size_t)(m0 + row) * K + kof;
        boff[i] = (size_t)(n0 + row) * K + kof;
        dofs[i] = c * 8;
    }

    f32x4 acc[4][4];
#pragma unroll
    for (int i = 0; i < 4; ++i)
#pragma unroll
        for (int j = 0; j < 4; ++j) acc[i][j] = (f32x4){0.f, 0.f, 0.f, 0.f};

    for (int t = 0; t < 32; ++t) {
        const int kk = t * 32;
        uint4 av[2], bv[2];
#pragma unroll
        for (int i = 0; i < 2; ++i) {
            av[i] = *(const uint4*)(Ap + aoff[i] + kk);
            bv[i] = *(const uint4*)(W + boff[i] + kk);
        }
#pragma unroll
        for (int i = 0; i < 2; ++i) {
            *(uint4*)(&As[dofs[i]]) = av[i];
            *(uint4*)(&Bs[dofs[i]]) = bv[i];
        }
        __syncthreads();

        bf16x8 af[4], bfr[4];
#pragma unroll
        for (int mi = 0; mi < 4; ++mi)
            af[mi] = *(const bf16x8*)(&As[(wr * 4 + mi) * 512 + lane * 8]);
#pragma unroll
        for (int ni = 0; ni < 4; ++ni)
            bfr[ni] = *(const bf16x8*)(&Bs[(wc * 4 + ni) * 512 + lane * 8]);
#pragma unroll
        for (int mi = 0; mi < 4; ++mi)
#pragma unroll
            for (int ni = 0; ni < 4; ++ni)
                acc[mi][ni] = mfma16(af[mi], bfr[ni], acc[mi][ni]);
        __syncthreads();
    }

#pragma unroll
    for (int mi = 0; mi < 4; ++mi)
#pragma unroll
        for (int ni = 0; ni < 4; ++ni)
#pragma unroll
            for (int r = 0; r < 4; ++r) {
                const int row = m0 + wr * 64 + mi * 16 + rowg * 4 + r;
                const int col = n0 + wc * 64 + ni * 16 + colg;
                Cp[(size_t)row * N + col] = acc[mi][ni][r];
            }
}

// ---------------------------------------------------------------------------
// Flash attention v3 (unchanged): 4-wave blocks, block-staged K/V in swizzled
// LDS, swapped QK^T (lane-local softmax), defer-rescale.
// ---------------------------------------------------------------------------
constexpr float CEXP = 0.18033688011112042f;  // 0.125 * log2(e)

__global__ __launch_bounds__(256) void attn_causal(const u16* __restrict__ Qp,
                                                   const u16* __restrict__ Kp,
                                                   const u16* __restrict__ Vt,
                                                   u16* __restrict__ concat) {
    constexpr int T = 2048, C = 1024;
    __shared__ __align__(16) u16 Ks[128 * 64];
    __shared__ __align__(16) u16 Vs[64 * 128];
    __shared__ __align__(16) u16 Pl[4][2048];

    const int tid  = threadIdx.x;
    const int lane = tid & 63;
    const int w    = tid >> 6;
    const int colg = lane & 15, rowg = lane >> 4;

    const int idx = blockIdx.x;
    const int xcd = idx & 7;
    const int i1  = idx >> 3;
    const int bh  = xcd * 4 + (i1 & 3);
    const int qg  = 31 - (i1 >> 2);
    const int b = bh >> 4, h = bh & 15;

    const int q0 = (qg * 4 + w) * 16;
    const int nt    = (q0 + 143) >> 7;
    const int ktmax = ((qg * 4 + 3) * 16 + 143) >> 7;

    const char* Kg = (const char*)(Kp + (size_t)(b * T) * C + h * 64);
    const char* Vg = (const char*)(Vt + ((size_t)(b * 16 + h) * 64) * T);
    char* Ksb = (char*)Ks;
    char* Vsb = (char*)Vs;
    char* Pw  = (char*)&Pl[w][0];

    const u16* Qb = Qp + (size_t)(b * T + q0 + colg) * C + h * 64;
    const bf16x8 qf0 = *(const bf16x8*)(Qb + rowg * 8);
    const bf16x8 qf1 = *(const bf16x8*)(Qb + 32 + rowg * 8);

    float mm = -1e30f, ll = 0.f;
    f32x4 O[4];
#pragma unroll
    for (int g = 0; g < 4; ++g) O[g] = (f32x4){0.f, 0.f, 0.f, 0.f};

    const int sw = (colg & 7) << 4;

    for (int kt = 0; kt < ktmax; ++kt) {
        const int kvb = kt * 128;
        uint4 kst[4], vst[4];
#pragma unroll
        for (int i2 = 0; i2 < 4; ++i2) {
            const int s  = i2 * 4096 + tid * 16;
            const int kv = s >> 7, ir = s & 127;
            kst[i2] = *(const uint4*)(Kg + (size_t)(kvb + kv) * 2048 + ir);
            const int d = s >> 8, irv = s & 255;
            vst[i2] = *(const uint4*)(Vg + (size_t)d * 4096 + (size_t)kvb * 2 + irv);
        }
#pragma unroll
        for (int i2 = 0; i2 < 4; ++i2) {
            const int s  = i2 * 4096 + tid * 16;
            const int kv = s >> 7;
            *(uint4*)(Ksb + (s ^ ((kv & 7) << 4))) = kst[i2];
            const int d = s >> 8;
            *(uint4*)(Vsb + (s ^ ((d & 7) << 4))) = vst[i2];
        }
        __syncthreads();

        if (kt < nt) {
            float pr[8][4];
#pragma unroll
            for (int sub = 0; sub < 8; ++sub) {
                const int kb = (sub * 16 + colg) * 128 + rowg * 16;
                bf16x8 kf0 = *(const bf16x8*)(Ksb + (kb ^ sw));
                bf16x8 kf1 = *(const bf16x8*)(Ksb + ((kb + 64) ^ sw));
                f32x4 t = (f32x4){0.f, 0.f, 0.f, 0.f};
                t = mfma16(kf0, qf0, t);
                t = mfma16(kf1, qf1, t);
#pragma unroll
                for (int r = 0; r < 4; ++r) pr[sub][r] = t[r];
            }
            if (kvb + 127 > q0) {
#pragma unroll
                for (int sub = 0; sub < 8; ++sub)
#pragma unroll
                    for (int r = 0; r < 4; ++r)
                        if (kvb + sub * 16 + rowg * 4 + r > q0 + colg) pr[sub][r] = -1e30f;
            }
            float mx[8];
#pragma unroll
            for (int sub = 0; sub < 8; ++sub)
                mx[sub] = fmaxf(fmaxf(pr[sub][0], pr[sub][1]), fmaxf(pr[sub][2], pr[sub][3]));
            float pm = fmaxf(fmaxf(fmaxf(mx[0], mx[1]), fmaxf(mx[2], mx[3])),
                             fmaxf(fmaxf(mx[4], mx[5]), fmaxf(mx[6], mx[7])));
            pm = fmaxf(pm, __shfl_xor(pm, 16, 64));
            pm = fmaxf(pm, __shfl_xor(pm, 32, 64));
            if (__any(pm > mm + 40.f)) {
                const float mn = fmaxf(mm, pm);
                const float sc = __builtin_amdgcn_exp2f((mm - mn) * CEXP);
                mm = mn;
                ll *= sc;
#pragma unroll
                for (int r = 0; r < 4; ++r) {
                    const float scr = __shfl(sc, (lane & 48) + rowg * 4 + r, 64);
#pragma unroll
                    for (int g = 0; g < 4; ++g) O[g][r] *= scr;
                }
            }
            float rs = 0.f;
#pragma unroll
            for (int sub = 0; sub < 8; ++sub) {
                const float e0 = __builtin_amdgcn_exp2f((pr[sub][0] - mm) * CEXP);
                const float e1 = __builtin_amdgcn_exp2f((pr[sub][1] - mm) * CEXP);
                const float e2 = __builtin_amdgcn_exp2f((pr[sub][2] - mm) * CEXP);
                const float e3 = __builtin_amdgcn_exp2f((pr[sub][3] - mm) * CEXP);
                pr[sub][0] = e0; pr[sub][1] = e1; pr[sub][2] = e2; pr[sub][3] = e3;
                rs += (e0 + e1) + (e2 + e3);
            }
            rs += __shfl_xor(rs, 16, 64);
            rs += __shfl_xor(rs, 32, 64);
            ll += rs;
#pragma unroll
            for (int sub = 0; sub < 8; ++sub) {
                uint2 pk;
                pk.x = (unsigned)f2bf(pr[sub][0]) | ((unsigned)f2bf(pr[sub][1]) << 16);
                pk.y = (unsigned)f2bf(pr[sub][2]) | ((unsigned)f2bf(pr[sub][3]) << 16);
                const int wb = (colg * 256 + sub * 32 + rowg * 8) ^ sw;
                *(uint2*)(Pw + wb) = pk;
            }
            bf16x8 pf[4];
#pragma unroll
            for (int kc = 0; kc < 4; ++kc)
                pf[kc] = *(const bf16x8*)(Pw + ((colg * 256 + kc * 64 + rowg * 16) ^ sw));
#pragma unroll
            for (int g = 0; g < 4; ++g) {
                const int vb0 = (g * 16 + colg) * 256 + rowg * 16;
#pragma unroll
                for (int kc = 0; kc < 4; ++kc) {
                    bf16x8 vf = *(const bf16x8*)(Vsb + ((vb0 + kc * 64) ^ sw));
                    O[g] = mfma16(pf[kc], vf, O[g]);
                }
            }
        }
        __syncthreads();
    }

#pragma unroll
    for (int r = 0; r < 4; ++r) {
        const float lr = __shfl(ll, (lane & 48) + rowg * 4 + r, 64);
        const float rc = 1.f / lr;
        const size_t base = (size_t)(b * T + q0 + rowg * 4 + r) * C + h * 64;
#pragma unroll
        for (int g = 0; g < 4; ++g)
            concat[base + g * 16 + colg] = f2bf(O[g][r] * rc);
    }
}

// ---------------------------------------------------------------------------
extern "C" void kernel_launch(void* const* d_in, const int* in_sizes, int n_in,
                              void* d_out, int out_size, void* d_ws, size_t ws_size,
                              hipStream_t stream) {
    const float* q  = (const float*)d_in[0];
    const float* k  = (const float*)d_in[1];
    const float* v  = (const float*)d_in[2];
    const float* Wq = (const float*)d_in[3];
    const float* Wk = (const float*)d_in[4];
    const float* Wv = (const float*)d_in[5];
    const float* Wo = (const float*)d_in[6];
    float* out = (float*)d_out;

    constexpr size_t NELEM = (size_t)4096 * 1024;  // 4M
    constexpr size_t WSZ   = (size_t)1 << 20;      // 1M
    u16* Wbf = (u16*)d_ws;          // bf16 weights    4M
    u16* Qp  = Wbf + 4 * WSZ;       // proj Q          4M
    u16* Kp  = Qp + NELEM;          // proj K          4M
    u16* Vt  = Kp + NELEM;          // proj V (transp) 4M
    u16* Cc  = Vt + NELEM;          // attn concat     4M

    cvtW<<<2048, 256, 0, stream>>>(Wq, Wk, Wv, Wo, Wbf);

    gemm_qkv<<<768, 256, 0, stream>>>(q, k, v, Wbf, Qp, Kp, Vt);

    attn_causal<<<1024, 256, 0, stream>>>(Qp, Kp, Vt, Cc);

    gemm_out<<<256, 256, 0, stream>>>(Cc, Wbf + 3 * WSZ, out);
}

// Round 11
// 137.999 us; speedup vs baseline: 1.3620x; 1.3062x over previous
//
#include <hip/hip_runtime.h>
#include <hip/hip_bf16.h>

typedef __bf16 bf16x8 __attribute__((ext_vector_type(8)));
typedef float  f32x4  __attribute__((ext_vector_type(4)));
typedef unsigned short u16;

__device__ __forceinline__ u16 f2bf(float f) {
    __bf16 h = (__bf16)f;
    return __builtin_bit_cast(u16, h);
}

__device__ __forceinline__ f32x4 mfma16(bf16x8 a, bf16x8 b, f32x4 c) {
    return __builtin_amdgcn_mfma_f32_16x16x32_bf16(a, b, c, 0, 0, 0);
}

// ---------------------------------------------------------------------------
// cvtW: Wq,Wk,Wv,Wo (1M elems each) fp32 -> bf16 concatenated.
// ---------------------------------------------------------------------------
__global__ __launch_bounds__(256) void cvtW(const float* __restrict__ W0,
                                            const float* __restrict__ W1,
                                            const float* __restrict__ W2,
                                            const float* __restrict__ W3,
                                            u16* __restrict__ dst) {
    const int t     = blockIdx.x * 256 + threadIdx.x;   // 0..512K-1
    const int which = t >> 17;
    const int off   = (t & 0x1FFFF) * 8;
    const float* s  = (which == 0) ? W0 : (which == 1) ? W1 : (which == 2) ? W2 : W3;
    float4 f0 = *(const float4*)(s + off);
    float4 f1 = *(const float4*)(s + off + 4);
    bf16x8 u;
    u[0] = (__bf16)f0.x; u[1] = (__bf16)f0.y; u[2] = (__bf16)f0.z; u[3] = (__bf16)f0.w;
    u[4] = (__bf16)f1.x; u[5] = (__bf16)f1.y; u[6] = (__bf16)f1.z; u[7] = (__bf16)f1.w;
    *(bf16x8*)(dst + ((size_t)which << 20) + off) = u;
}

// ---------------------------------------------------------------------------
// Merged Q/K/V GEMM — r6 structure exactly (reg-staged both operands,
// BK=32, single-buffered row-major [row][32] LDS, quad-contiguous global
// loads) + LDS XOR swizzle: 16B-slot column kc' = kc ^ ((row>>1)&3) applied
// on BOTH ds_write and ds_read. Kills r6's 8-way read conflict while
// keeping r6's global coalescing untouched.
// ---------------------------------------------------------------------------
__global__ __launch_bounds__(256) void gemm_qkv(const float* __restrict__ q,
                                                const float* __restrict__ k,
                                                const float* __restrict__ v,
                                                const u16* __restrict__ Wb,
                                                u16* __restrict__ Qp,
                                                u16* __restrict__ Kp,
                                                u16* __restrict__ Vt) {
    constexpr int K = 1024, N = 1024;
    __shared__ __align__(16) u16 As[128 * 32];   // 8 KB
    __shared__ __align__(16) u16 Bs[128 * 32];   // 8 KB

    const int tid  = threadIdx.x;
    const int lane = tid & 63;
    const int w    = tid >> 6;
    const int wr = w >> 1, wc = w & 1;
    const int wg    = (blockIdx.x & 7) * 96 + (blockIdx.x >> 3);  // XCD swizzle
    const int which = wg >> 8;
    const int inner = wg & 255;
    const int m0 = (inner >> 3) * 128, n0 = (inner & 7) * 128;
    const int colg = lane & 15, rowg = lane >> 4;

    const float* A = (which == 0) ? q : (which == 1) ? k : v;
    const u16*   W = Wb + ((size_t)which << 20);

    // staging map (r6): chunk c -> row=c>>2, kc=c&3 (quad-contiguous global)
    size_t aoff[2], boff[2];
    int wio[2];
#pragma unroll
    for (int i = 0; i < 2; ++i) {
        const int c   = i * 256 + tid;
        const int row = c >> 2;
        const int kc  = c & 3;
        aoff[i] = (size_t)(m0 + row) * K + kc * 8;   // floats
        boff[i] = (size_t)(n0 + row) * K + kc * 8;   // u16s
        const int kcs = kc ^ ((row >> 1) & 3);       // swizzled 16B slot
        wio[i] = row * 32 + kcs * 8;                 // u16 index
    }
    // fragment read offset (lane-constant): row=colg, kc=rowg swizzled
    const int kcr  = rowg ^ ((colg >> 1) & 3);
    const int rbase = colg * 32 + kcr * 8;

    f32x4 acc[4][4];
#pragma unroll
    for (int i = 0; i < 4; ++i)
#pragma unroll
        for (int j = 0; j < 4; ++j) acc[i][j] = (f32x4){0.f, 0.f, 0.f, 0.f};

    for (int t = 0; t < 32; ++t) {
        const int kk = t * 32;
        float4 a0[2], a1[2];
        uint4  bv[2];
#pragma unroll
        for (int i = 0; i < 2; ++i) {
            a0[i] = *(const float4*)(A + aoff[i] + kk);
            a1[i] = *(const float4*)(A + aoff[i] + kk + 4);
            bv[i] = *(const uint4*)(W + boff[i] + kk);
        }
#pragma unroll
        for (int i = 0; i < 2; ++i) {
            bf16x8 u;
            u[0] = (__bf16)a0[i].x; u[1] = (__bf16)a0[i].y;
            u[2] = (__bf16)a0[i].z; u[3] = (__bf16)a0[i].w;
            u[4] = (__bf16)a1[i].x; u[5] = (__bf16)a1[i].y;
            u[6] = (__bf16)a1[i].z; u[7] = (__bf16)a1[i].w;
            *(bf16x8*)(&As[wio[i]]) = u;
            *(uint4*)(&Bs[wio[i]]) = bv[i];
        }
        __syncthreads();

        bf16x8 af[4], bfr[4];
#pragma unroll
        for (int mi = 0; mi < 4; ++mi)
            af[mi] = *(const bf16x8*)(&As[(wr * 64 + mi * 16) * 32 + rbase]);
#pragma unroll
        for (int ni = 0; ni < 4; ++ni)
            bfr[ni] = *(const bf16x8*)(&Bs[(wc * 64 + ni * 16) * 32 + rbase]);
#pragma unroll
        for (int mi = 0; mi < 4; ++mi)
#pragma unroll
            for (int ni = 0; ni < 4; ++ni)
                acc[mi][ni] = mfma16(af[mi], bfr[ni], acc[mi][ni]);
        __syncthreads();
    }

    u16* Crm = (which == 0) ? Qp : Kp;
#pragma unroll
    for (int mi = 0; mi < 4; ++mi) {
#pragma unroll
        for (int ni = 0; ni < 4; ++ni) {
#pragma unroll
            for (int r = 0; r < 4; ++r) {
                const int row = m0 + wr * 64 + mi * 16 + rowg * 4 + r;
                const int col = n0 + wc * 64 + ni * 16 + colg;
                const float vv = acc[mi][ni][r];
                if (which < 2) {
                    Crm[(size_t)row * N + col] = f2bf(vv);
                } else {
                    const int b = row >> 11, tt = row & 2047;
                    const int h = col >> 6,  d = col & 63;
                    Vt[((size_t)((b * 16 + h) * 64 + d) << 11) + tt] = f2bf(vv);
                }
            }
        }
    }
}

// ---------------------------------------------------------------------------
// Output GEMM — r6 structure (64x128 tile, 512 blocks, bf16 reg-staged)
// + the same LDS XOR swizzle. fp32 out.
// ---------------------------------------------------------------------------
__global__ __launch_bounds__(256) void gemm_out(const u16* __restrict__ Ap,
                                                const u16* __restrict__ W,
                                                float* __restrict__ Cp) {
    constexpr int K = 1024, N = 1024;
    __shared__ __align__(16) u16 As[64 * 32];    // 4 KB
    __shared__ __align__(16) u16 Bs[128 * 32];   // 8 KB

    const int tid  = threadIdx.x;
    const int lane = tid & 63;
    const int w    = tid >> 6;
    const int wr = w >> 1, wc = w & 1;
    const int wg = (blockIdx.x & 7) * 64 + (blockIdx.x >> 3);  // XCD swizzle
    const int m0 = (wg >> 3) * 64, n0 = (wg & 7) * 128;
    const int colg = lane & 15, rowg = lane >> 4;

    // A: 256 chunks (64 rows x 4 kc); B: 512 chunks
    const int rowA = tid >> 2, kcA = tid & 3;
    const size_t aoff = (size_t)(m0 + rowA) * K + kcA * 8;
    const int wiA = rowA * 32 + (kcA ^ ((rowA >> 1) & 3)) * 8;

    size_t boff[2];
    int wiB[2];
#pragma unroll
    for (int i = 0; i < 2; ++i) {
        const int c   = i * 256 + tid;
        const int row = c >> 2;
        const int kc  = c & 3;
        boff[i] = (size_t)(n0 + row) * K + kc * 8;
        wiB[i] = row * 32 + (kc ^ ((row >> 1) & 3)) * 8;
    }
    const int kcr   = rowg ^ ((colg >> 1) & 3);
    const int rbase = colg * 32 + kcr * 8;

    f32x4 acc[2][4];
#pragma unroll
    for (int i = 0; i < 2; ++i)
#pragma unroll
        for (int j = 0; j < 4; ++j) acc[i][j] = (f32x4){0.f, 0.f, 0.f, 0.f};

    for (int t = 0; t < 32; ++t) {
        const int kk = t * 32;
        uint4 av = *(const uint4*)(Ap + aoff + kk);
        uint4 bv[2];
#pragma unroll
        for (int i = 0; i < 2; ++i) bv[i] = *(const uint4*)(W + boff[i] + kk);
        *(uint4*)(&As[wiA]) = av;
#pragma unroll
        for (int i = 0; i < 2; ++i) *(uint4*)(&Bs[wiB[i]]) = bv[i];
        __syncthreads();

        bf16x8 af[2], bfr[4];
#pragma unroll
        for (int mi = 0; mi < 2; ++mi)
            af[mi] = *(const bf16x8*)(&As[(wr * 32 + mi * 16) * 32 + rbase]);
#pragma unroll
        for (int ni = 0; ni < 4; ++ni)
            bfr[ni] = *(const bf16x8*)(&Bs[(wc * 64 + ni * 16) * 32 + rbase]);
#pragma unroll
        for (int mi = 0; mi < 2; ++mi)
#pragma unroll
            for (int ni = 0; ni < 4; ++ni)
                acc[mi][ni] = mfma16(af[mi], bfr[ni], acc[mi][ni]);
        __syncthreads();
    }

#pragma unroll
    for (int mi = 0; mi < 2; ++mi)
#pragma unroll
        for (int ni = 0; ni < 4; ++ni)
#pragma unroll
            for (int r = 0; r < 4; ++r) {
                const int row = m0 + wr * 32 + mi * 16 + rowg * 4 + r;
                const int col = n0 + wc * 64 + ni * 16 + colg;
                Cp[(size_t)row * N + col] = acc[mi][ni][r];
            }
}

// ---------------------------------------------------------------------------
// Flash attention v3 (unchanged): 4-wave blocks, block-staged K/V in swizzled
// LDS, swapped QK^T (lane-local softmax), defer-rescale.
// ---------------------------------------------------------------------------
constexpr float CEXP = 0.18033688011112042f;  // 0.125 * log2(e)

__global__ __launch_bounds__(256) void attn_causal(const u16* __restrict__ Qp,
                                                   const u16* __restrict__ Kp,
                                                   const u16* __restrict__ Vt,
                                                   u16* __restrict__ concat) {
    constexpr int T = 2048, C = 1024;
    __shared__ __align__(16) u16 Ks[128 * 64];
    __shared__ __align__(16) u16 Vs[64 * 128];
    __shared__ __align__(16) u16 Pl[4][2048];

    const int tid  = threadIdx.x;
    const int lane = tid & 63;
    const int w    = tid >> 6;
    const int colg = lane & 15, rowg = lane >> 4;

    const int idx = blockIdx.x;
    const int xcd = idx & 7;
    const int i1  = idx >> 3;
    const int bh  = xcd * 4 + (i1 & 3);
    const int qg  = 31 - (i1 >> 2);
    const int b = bh >> 4, h = bh & 15;

    const int q0 = (qg * 4 + w) * 16;
    const int nt    = (q0 + 143) >> 7;
    const int ktmax = ((qg * 4 + 3) * 16 + 143) >> 7;

    const char* Kg = (const char*)(Kp + (size_t)(b * T) * C + h * 64);
    const char* Vg = (const char*)(Vt + ((size_t)(b * 16 + h) * 64) * T);
    char* Ksb = (char*)Ks;
    char* Vsb = (char*)Vs;
    char* Pw  = (char*)&Pl[w][0];

    const u16* Qb = Qp + (size_t)(b * T + q0 + colg) * C + h * 64;
    const bf16x8 qf0 = *(const bf16x8*)(Qb + rowg * 8);
    const bf16x8 qf1 = *(const bf16x8*)(Qb + 32 + rowg * 8);

    float mm = -1e30f, ll = 0.f;
    f32x4 O[4];
#pragma unroll
    for (int g = 0; g < 4; ++g) O[g] = (f32x4){0.f, 0.f, 0.f, 0.f};

    const int sw = (colg & 7) << 4;

    for (int kt = 0; kt < ktmax; ++kt) {
        const int kvb = kt * 128;
        uint4 kst[4], vst[4];
#pragma unroll
        for (int i2 = 0; i2 < 4; ++i2) {
            const int s  = i2 * 4096 + tid * 16;
            const int kv = s >> 7, ir = s & 127;
            kst[i2] = *(const uint4*)(Kg + (size_t)(kvb + kv) * 2048 + ir);
            const int d = s >> 8, irv = s & 255;
            vst[i2] = *(const uint4*)(Vg + (size_t)d * 4096 + (size_t)kvb * 2 + irv);
        }
#pragma unroll
        for (int i2 = 0; i2 < 4; ++i2) {
            const int s  = i2 * 4096 + tid * 16;
            const int kv = s >> 7;
            *(uint4*)(Ksb + (s ^ ((kv & 7) << 4))) = kst[i2];
            const int d = s >> 8;
            *(uint4*)(Vsb + (s ^ ((d & 7) << 4))) = vst[i2];
        }
        __syncthreads();

        if (kt < nt) {
            float pr[8][4];
#pragma unroll
            for (int sub = 0; sub < 8; ++sub) {
                const int kb = (sub * 16 + colg) * 128 + rowg * 16;
                bf16x8 kf0 = *(const bf16x8*)(Ksb + (kb ^ sw));
                bf16x8 kf1 = *(const bf16x8*)(Ksb + ((kb + 64) ^ sw));
                f32x4 t = (f32x4){0.f, 0.f, 0.f, 0.f};
                t = mfma16(kf0, qf0, t);
                t = mfma16(kf1, qf1, t);
#pragma unroll
                for (int r = 0; r < 4; ++r) pr[sub][r] = t[r];
            }
            if (kvb + 127 > q0) {
#pragma unroll
                for (int sub = 0; sub < 8; ++sub)
#pragma unroll
                    for (int r = 0; r < 4; ++r)
                        if (kvb + sub * 16 + rowg * 4 + r > q0 + colg) pr[sub][r] = -1e30f;
            }
            float mx[8];
#pragma unroll
            for (int sub = 0; sub < 8; ++sub)
                mx[sub] = fmaxf(fmaxf(pr[sub][0], pr[sub][1]), fmaxf(pr[sub][2], pr[sub][3]));
            float pm = fmaxf(fmaxf(fmaxf(mx[0], mx[1]), fmaxf(mx[2], mx[3])),
                             fmaxf(fmaxf(mx[4], mx[5]), fmaxf(mx[6], mx[7])));
            pm = fmaxf(pm, __shfl_xor(pm, 16, 64));
            pm = fmaxf(pm, __shfl_xor(pm, 32, 64));
            if (__any(pm > mm + 40.f)) {
                const float mn = fmaxf(mm, pm);
                const float sc = __builtin_amdgcn_exp2f((mm - mn) * CEXP);
                mm = mn;
                ll *= sc;
#pragma unroll
                for (int r = 0; r < 4; ++r) {
                    const float scr = __shfl(sc, (lane & 48) + rowg * 4 + r, 64);
#pragma unroll
                    for (int g = 0; g < 4; ++g) O[g][r] *= scr;
                }
            }
            float rs = 0.f;
#pragma unroll
            for (int sub = 0; sub < 8; ++sub) {
                const float e0 = __builtin_amdgcn_exp2f((pr[sub][0] - mm) * CEXP);
                const float e1 = __builtin_amdgcn_exp2f((pr[sub][1] - mm) * CEXP);
                const float e2 = __builtin_amdgcn_exp2f((pr[sub][2] - mm) * CEXP);
                const float e3 = __builtin_amdgcn_exp2f((pr[sub][3] - mm) * CEXP);
                pr[sub][0] = e0; pr[sub][1] = e1; pr[sub][2] = e2; pr[sub][3] = e3;
                rs += (e0 + e1) + (e2 + e3);
            }
            rs += __shfl_xor(rs, 16, 64);
            rs += __shfl_xor(rs, 32, 64);
            ll += rs;
#pragma unroll
            for (int sub = 0; sub < 8; ++sub) {
                uint2 pk;
                pk.x = (unsigned)f2bf(pr[sub][0]) | ((unsigned)f2bf(pr[sub][1]) << 16);
                pk.y = (unsigned)f2bf(pr[sub][2]) | ((unsigned)f2bf(pr[sub][3]) << 16);
                const int wb = (colg * 256 + sub * 32 + rowg * 8) ^ sw;
                *(uint2*)(Pw + wb) = pk;
            }
            bf16x8 pf[4];
#pragma unroll
            for (int kc = 0; kc < 4; ++kc)
                pf[kc] = *(const bf16x8*)(Pw + ((colg * 256 + kc * 64 + rowg * 16) ^ sw));
#pragma unroll
            for (int g = 0; g < 4; ++g) {
                const int vb0 = (g * 16 + colg) * 256 + rowg * 16;
#pragma unroll
                for (int kc = 0; kc < 4; ++kc) {
                    bf16x8 vf = *(const bf16x8*)(Vsb + ((vb0 + kc * 64) ^ sw));
                    O[g] = mfma16(pf[kc], vf, O[g]);
                }
            }
        }
        __syncthreads();
    }

#pragma unroll
    for (int r = 0; r < 4; ++r) {
        const float lr = __shfl(ll, (lane & 48) + rowg * 4 + r, 64);
        const float rc = 1.f / lr;
        const size_t base = (size_t)(b * T + q0 + rowg * 4 + r) * C + h * 64;
#pragma unroll
        for (int g = 0; g < 4; ++g)
            concat[base + g * 16 + colg] = f2bf(O[g][r] * rc);
    }
}

// ---------------------------------------------------------------------------
extern "C" void kernel_launch(void* const* d_in, const int* in_sizes, int n_in,
                              void* d_out, int out_size, void* d_ws, size_t ws_size,
                              hipStream_t stream) {
    const float* q  = (const float*)d_in[0];
    const float* k  = (const float*)d_in[1];
    const float* v  = (const float*)d_in[2];
    const float* Wq = (const float*)d_in[3];
    const float* Wk = (const float*)d_in[4];
    const float* Wv = (const float*)d_in[5];
    const float* Wo = (const float*)d_in[6];
    float* out = (float*)d_out;

    constexpr size_t NELEM = (size_t)4096 * 1024;  // 4M
    constexpr size_t WSZ   = (size_t)1 << 20;      // 1M
    u16* Wbf = (u16*)d_ws;          // bf16 weights    4M
    u16* Qp  = Wbf + 4 * WSZ;       // proj Q          4M
    u16* Kp  = Qp + NELEM;          // proj K          4M
    u16* Vt  = Kp + NELEM;          // proj V (transp) 4M
    u16* Cc  = Vt + NELEM;          // attn concat     4M

    cvtW<<<2048, 256, 0, stream>>>(Wq, Wk, Wv, Wo, Wbf);

    gemm_qkv<<<768, 256, 0, stream>>>(q, k, v, Wbf, Qp, Kp, Vt);

    attn_causal<<<1024, 256, 0, stream>>>(Qp, Kp, Vt, Cc);

    gemm_out<<<512, 256, 0, stream>>>(Cc, Wbf + 3 * WSZ, out);
}

// Round 12
// 134.424 us; speedup vs baseline: 1.3982x; 1.0266x over previous
//
#include <hip/hip_runtime.h>
#include <hip/hip_bf16.h>

typedef __bf16 bf16x8 __attribute__((ext_vector_type(8)));
typedef float  f32x4  __attribute__((ext_vector_type(4)));
typedef unsigned short u16;

__device__ __forceinline__ u16 f2bf(float f) {
    __bf16 h = (__bf16)f;
    return __builtin_bit_cast(u16, h);
}

__device__ __forceinline__ f32x4 mfma16(bf16x8 a, bf16x8 b, f32x4 c) {
    return __builtin_amdgcn_mfma_f32_16x16x32_bf16(a, b, c, 0, 0, 0);
}

__device__ __forceinline__ bf16x8 cvt8(float4 a0, float4 a1) {
    bf16x8 u;
    u[0] = (__bf16)a0.x; u[1] = (__bf16)a0.y; u[2] = (__bf16)a0.z; u[3] = (__bf16)a0.w;
    u[4] = (__bf16)a1.x; u[5] = (__bf16)a1.y; u[6] = (__bf16)a1.z; u[7] = (__bf16)a1.w;
    return u;
}

// ---------------------------------------------------------------------------
// cvtW: Wq,Wk,Wv,Wo (1M elems each) fp32 -> bf16 concatenated.
// ---------------------------------------------------------------------------
__global__ __launch_bounds__(256) void cvtW(const float* __restrict__ W0,
                                            const float* __restrict__ W1,
                                            const float* __restrict__ W2,
                                            const float* __restrict__ W3,
                                            u16* __restrict__ dst) {
    const int t     = blockIdx.x * 256 + threadIdx.x;   // 0..512K-1
    const int which = t >> 17;
    const int off   = (t & 0x1FFFF) * 8;
    const float* s  = (which == 0) ? W0 : (which == 1) ? W1 : (which == 2) ? W2 : W3;
    float4 f0 = *(const float4*)(s + off);
    float4 f1 = *(const float4*)(s + off + 4);
    *(bf16x8*)(dst + ((size_t)which << 20) + off) = cvt8(f0, f1);
}

// ---------------------------------------------------------------------------
// Merged Q/K/V GEMM — r11 layout (swizzled LDS, quad-contiguous global,
// BK=32, 128x128, 4 waves, 768 blocks) + reg-staged 2-phase pipeline:
// loads(t+1) issued BEFORE compute(t); LDS double-buffered; ONE barrier/iter.
// No global_load_lds anywhere => vmcnt wait at ds_write drains only its own
// loads (the r9 DMA cross-drain bug is structurally impossible here).
// ---------------------------------------------------------------------------
__global__ __launch_bounds__(256) void gemm_qkv(const float* __restrict__ q,
                                                const float* __restrict__ k,
                                                const float* __restrict__ v,
                                                const u16* __restrict__ Wb,
                                                u16* __restrict__ Qp,
                                                u16* __restrict__ Kp,
                                                u16* __restrict__ Vt) {
    constexpr int K = 1024, N = 1024;
    __shared__ __align__(16) u16 As[2][4096];   // 2 x 8 KB
    __shared__ __align__(16) u16 Bs[2][4096];   // 2 x 8 KB

    const int tid  = threadIdx.x;
    const int lane = tid & 63;
    const int w    = tid >> 6;
    const int wr = w >> 1, wc = w & 1;
    const int wg    = (blockIdx.x & 7) * 96 + (blockIdx.x >> 3);  // XCD swizzle
    const int which = wg >> 8;
    const int inner = wg & 255;
    const int m0 = (inner >> 3) * 128, n0 = (inner & 7) * 128;
    const int colg = lane & 15, rowg = lane >> 4;

    const float* A = (which == 0) ? q : (which == 1) ? k : v;
    const u16*   W = Wb + ((size_t)which << 20);

    // staging map: chunk c -> row=c>>2, kc=c&3 (quad-contiguous global)
    size_t aoff[2], boff[2];
    int wio[2];
#pragma unroll
    for (int i = 0; i < 2; ++i) {
        const int c   = i * 256 + tid;
        const int row = c >> 2;
        const int kc  = c & 3;
        aoff[i] = (size_t)(m0 + row) * K + kc * 8;   // floats
        boff[i] = (size_t)(n0 + row) * K + kc * 8;   // u16s
        const int kcs = kc ^ ((row >> 1) & 3);       // swizzled 16B slot
        wio[i] = row * 32 + kcs * 8;                 // u16 index
    }
    // fragment read offset (lane-constant): row=colg, kc=rowg swizzled
    const int kcr   = rowg ^ ((colg >> 1) & 3);
    const int rbase = colg * 32 + kcr * 8;

    f32x4 acc[4][4];
#pragma unroll
    for (int i = 0; i < 4; ++i)
#pragma unroll
        for (int j = 0; j < 4; ++j) acc[i][j] = (f32x4){0.f, 0.f, 0.f, 0.f};

    // --- prologue: tile 0 -> regs -> LDS[0] ---
    float4 a0[2], a1[2];
    uint4  bv[2];
#pragma unroll
    for (int i = 0; i < 2; ++i) {
        a0[i] = *(const float4*)(A + aoff[i]);
        a1[i] = *(const float4*)(A + aoff[i] + 4);
        bv[i] = *(const uint4*)(W + boff[i]);
    }
#pragma unroll
    for (int i = 0; i < 2; ++i) {
        *(bf16x8*)(&As[0][wio[i]]) = cvt8(a0[i], a1[i]);
        *(uint4*)(&Bs[0][wio[i]]) = bv[i];
    }
    __syncthreads();

    int p = 0;
    for (int t = 0; t < 32; ++t) {
        // issue loads(t+1): latency flies under compute(t)
        if (t < 31) {
            const int kk = (t + 1) * 32;
#pragma unroll
            for (int i = 0; i < 2; ++i) {
                a0[i] = *(const float4*)(A + aoff[i] + kk);
                a1[i] = *(const float4*)(A + aoff[i] + kk + 4);
                bv[i] = *(const uint4*)(W + boff[i] + kk);
            }
        }
        // compute(t) from buf p
        {
            bf16x8 af[4], bfr[4];
#pragma unroll
            for (int mi = 0; mi < 4; ++mi)
                af[mi] = *(const bf16x8*)(&As[p][(wr * 64 + mi * 16) * 32 + rbase]);
#pragma unroll
            for (int ni = 0; ni < 4; ++ni)
                bfr[ni] = *(const bf16x8*)(&Bs[p][(wc * 64 + ni * 16) * 32 + rbase]);
#pragma unroll
            for (int mi = 0; mi < 4; ++mi)
#pragma unroll
                for (int ni = 0; ni < 4; ++ni)
                    acc[mi][ni] = mfma16(af[mi], bfr[ni], acc[mi][ni]);
        }
        // write(t+1) into the other buffer (readers of buf p unaffected)
        if (t < 31) {
#pragma unroll
            for (int i = 0; i < 2; ++i) {
                *(bf16x8*)(&As[p ^ 1][wio[i]]) = cvt8(a0[i], a1[i]);
                *(uint4*)(&Bs[p ^ 1][wio[i]]) = bv[i];
            }
        }
        __syncthreads();   // writes visible AND all reads of buf p done
        p ^= 1;
    }

    u16* Crm = (which == 0) ? Qp : Kp;
#pragma unroll
    for (int mi = 0; mi < 4; ++mi) {
#pragma unroll
        for (int ni = 0; ni < 4; ++ni) {
#pragma unroll
            for (int r = 0; r < 4; ++r) {
                const int row = m0 + wr * 64 + mi * 16 + rowg * 4 + r;
                const int col = n0 + wc * 64 + ni * 16 + colg;
                const float vv = acc[mi][ni][r];
                if (which < 2) {
                    Crm[(size_t)row * N + col] = f2bf(vv);
                } else {
                    const int b = row >> 11, tt = row & 2047;
                    const int h = col >> 6,  d = col & 63;
                    Vt[((size_t)((b * 16 + h) * 64 + d) << 11) + tt] = f2bf(vv);
                }
            }
        }
    }
}

// ---------------------------------------------------------------------------
// Output GEMM — r11 shape (64x128 tile, 512 blocks, bf16 reg-staged,
// swizzled LDS) + the same 2-phase pipeline. fp32 out.
// ---------------------------------------------------------------------------
__global__ __launch_bounds__(256) void gemm_out(const u16* __restrict__ Ap,
                                                const u16* __restrict__ W,
                                                float* __restrict__ Cp) {
    constexpr int K = 1024, N = 1024;
    __shared__ __align__(16) u16 As[2][2048];    // 2 x 4 KB
    __shared__ __align__(16) u16 Bs[2][4096];    // 2 x 8 KB

    const int tid  = threadIdx.x;
    const int lane = tid & 63;
    const int w    = tid >> 6;
    const int wr = w >> 1, wc = w & 1;
    const int wg = (blockIdx.x & 7) * 64 + (blockIdx.x >> 3);  // XCD swizzle
    const int m0 = (wg >> 3) * 64, n0 = (wg & 7) * 128;
    const int colg = lane & 15, rowg = lane >> 4;

    const int rowA = tid >> 2, kcA = tid & 3;
    const size_t aoff = (size_t)(m0 + rowA) * K + kcA * 8;
    const int wiA = rowA * 32 + (kcA ^ ((rowA >> 1) & 3)) * 8;

    size_t boff[2];
    int wiB[2];
#pragma unroll
    for (int i = 0; i < 2; ++i) {
        const int c   = i * 256 + tid;
        const int row = c >> 2;
        const int kc  = c & 3;
        boff[i] = (size_t)(n0 + row) * K + kc * 8;
        wiB[i] = row * 32 + (kc ^ ((row >> 1) & 3)) * 8;
    }
    const int kcr   = rowg ^ ((colg >> 1) & 3);
    const int rbase = colg * 32 + kcr * 8;

    f32x4 acc[2][4];
#pragma unroll
    for (int i = 0; i < 2; ++i)
#pragma unroll
        for (int j = 0; j < 4; ++j) acc[i][j] = (f32x4){0.f, 0.f, 0.f, 0.f};

    // prologue
    uint4 av = *(const uint4*)(Ap + aoff);
    uint4 bv[2];
#pragma unroll
    for (int i = 0; i < 2; ++i) bv[i] = *(const uint4*)(W + boff[i]);
    *(uint4*)(&As[0][wiA]) = av;
#pragma unroll
    for (int i = 0; i < 2; ++i) *(uint4*)(&Bs[0][wiB[i]]) = bv[i];
    __syncthreads();

    int p = 0;
    for (int t = 0; t < 32; ++t) {
        if (t < 31) {
            const int kk = (t + 1) * 32;
            av = *(const uint4*)(Ap + aoff + kk);
#pragma unroll
            for (int i = 0; i < 2; ++i) bv[i] = *(const uint4*)(W + boff[i] + kk);
        }
        {
            bf16x8 af[2], bfr[4];
#pragma unroll
            for (int mi = 0; mi < 2; ++mi)
                af[mi] = *(const bf16x8*)(&As[p][(wr * 32 + mi * 16) * 32 + rbase]);
#pragma unroll
            for (int ni = 0; ni < 4; ++ni)
                bfr[ni] = *(const bf16x8*)(&Bs[p][(wc * 64 + ni * 16) * 32 + rbase]);
#pragma unroll
            for (int mi = 0; mi < 2; ++mi)
#pragma unroll
                for (int ni = 0; ni < 4; ++ni)
                    acc[mi][ni] = mfma16(af[mi], bfr[ni], acc[mi][ni]);
        }
        if (t < 31) {
            *(uint4*)(&As[p ^ 1][wiA]) = av;
#pragma unroll
            for (int i = 0; i < 2; ++i) *(uint4*)(&Bs[p ^ 1][wiB[i]]) = bv[i];
        }
        __syncthreads();
        p ^= 1;
    }

#pragma unroll
    for (int mi = 0; mi < 2; ++mi)
#pragma unroll
        for (int ni = 0; ni < 4; ++ni)
#pragma unroll
            for (int r = 0; r < 4; ++r) {
                const int row = m0 + wr * 32 + mi * 16 + rowg * 4 + r;
                const int col = n0 + wc * 64 + ni * 16 + colg;
                Cp[(size_t)row * N + col] = acc[mi][ni][r];
            }
}

// ---------------------------------------------------------------------------
// Flash attention v3 (unchanged): 4-wave blocks, block-staged K/V in swizzled
// LDS, swapped QK^T (lane-local softmax), defer-rescale.
// ---------------------------------------------------------------------------
constexpr float CEXP = 0.18033688011112042f;  // 0.125 * log2(e)

__global__ __launch_bounds__(256) void attn_causal(const u16* __restrict__ Qp,
                                                   const u16* __restrict__ Kp,
                                                   const u16* __restrict__ Vt,
                                                   u16* __restrict__ concat) {
    constexpr int T = 2048, C = 1024;
    __shared__ __align__(16) u16 Ks[128 * 64];
    __shared__ __align__(16) u16 Vs[64 * 128];
    __shared__ __align__(16) u16 Pl[4][2048];

    const int tid  = threadIdx.x;
    const int lane = tid & 63;
    const int w    = tid >> 6;
    const int colg = lane & 15, rowg = lane >> 4;

    const int idx = blockIdx.x;
    const int xcd = idx & 7;
    const int i1  = idx >> 3;
    const int bh  = xcd * 4 + (i1 & 3);
    const int qg  = 31 - (i1 >> 2);
    const int b = bh >> 4, h = bh & 15;

    const int q0 = (qg * 4 + w) * 16;
    const int nt    = (q0 + 143) >> 7;
    const int ktmax = ((qg * 4 + 3) * 16 + 143) >> 7;

    const char* Kg = (const char*)(Kp + (size_t)(b * T) * C + h * 64);
    const char* Vg = (const char*)(Vt + ((size_t)(b * 16 + h) * 64) * T);
    char* Ksb = (char*)Ks;
    char* Vsb = (char*)Vs;
    char* Pw  = (char*)&Pl[w][0];

    const u16* Qb = Qp + (size_t)(b * T + q0 + colg) * C + h * 64;
    const bf16x8 qf0 = *(const bf16x8*)(Qb + rowg * 8);
    const bf16x8 qf1 = *(const bf16x8*)(Qb + 32 + rowg * 8);

    float mm = -1e30f, ll = 0.f;
    f32x4 O[4];
#pragma unroll
    for (int g = 0; g < 4; ++g) O[g] = (f32x4){0.f, 0.f, 0.f, 0.f};

    const int sw = (colg & 7) << 4;

    for (int kt = 0; kt < ktmax; ++kt) {
        const int kvb = kt * 128;
        uint4 kst[4], vst[4];
#pragma unroll
        for (int i2 = 0; i2 < 4; ++i2) {
            const int s  = i2 * 4096 + tid * 16;
            const int kv = s >> 7, ir = s & 127;
            kst[i2] = *(const uint4*)(Kg + (size_t)(kvb + kv) * 2048 + ir);
            const int d = s >> 8, irv = s & 255;
            vst[i2] = *(const uint4*)(Vg + (size_t)d * 4096 + (size_t)kvb * 2 + irv);
        }
#pragma unroll
        for (int i2 = 0; i2 < 4; ++i2) {
            const int s  = i2 * 4096 + tid * 16;
            const int kv = s >> 7;
            *(uint4*)(Ksb + (s ^ ((kv & 7) << 4))) = kst[i2];
            const int d = s >> 8;
            *(uint4*)(Vsb + (s ^ ((d & 7) << 4))) = vst[i2];
        }
        __syncthreads();

        if (kt < nt) {
            float pr[8][4];
#pragma unroll
            for (int sub = 0; sub < 8; ++sub) {
                const int kb = (sub * 16 + colg) * 128 + rowg * 16;
                bf16x8 kf0 = *(const bf16x8*)(Ksb + (kb ^ sw));
                bf16x8 kf1 = *(const bf16x8*)(Ksb + ((kb + 64) ^ sw));
                f32x4 t = (f32x4){0.f, 0.f, 0.f, 0.f};
                t = mfma16(kf0, qf0, t);
                t = mfma16(kf1, qf1, t);
#pragma unroll
                for (int r = 0; r < 4; ++r) pr[sub][r] = t[r];
            }
            if (kvb + 127 > q0) {
#pragma unroll
                for (int sub = 0; sub < 8; ++sub)
#pragma unroll
                    for (int r = 0; r < 4; ++r)
                        if (kvb + sub * 16 + rowg * 4 + r > q0 + colg) pr[sub][r] = -1e30f;
            }
            float mx[8];
#pragma unroll
            for (int sub = 0; sub < 8; ++sub)
                mx[sub] = fmaxf(fmaxf(pr[sub][0], pr[sub][1]), fmaxf(pr[sub][2], pr[sub][3]));
            float pm = fmaxf(fmaxf(fmaxf(mx[0], mx[1]), fmaxf(mx[2], mx[3])),
                             fmaxf(fmaxf(mx[4], mx[5]), fmaxf(mx[6], mx[7])));
            pm = fmaxf(pm, __shfl_xor(pm, 16, 64));
            pm = fmaxf(pm, __shfl_xor(pm, 32, 64));
            if (__any(pm > mm + 40.f)) {
                const float mn = fmaxf(mm, pm);
                const float sc = __builtin_amdgcn_exp2f((mm - mn) * CEXP);
                mm = mn;
                ll *= sc;
#pragma unroll
                for (int r = 0; r < 4; ++r) {
                    const float scr = __shfl(sc, (lane & 48) + rowg * 4 + r, 64);
#pragma unroll
                    for (int g = 0; g < 4; ++g) O[g][r] *= scr;
                }
            }
            float rs = 0.f;
#pragma unroll
            for (int sub = 0; sub < 8; ++sub) {
                const float e0 = __builtin_amdgcn_exp2f((pr[sub][0] - mm) * CEXP);
                const float e1 = __builtin_amdgcn_exp2f((pr[sub][1] - mm) * CEXP);
                const float e2 = __builtin_amdgcn_exp2f((pr[sub][2] - mm) * CEXP);
                const float e3 = __builtin_amdgcn_exp2f((pr[sub][3] - mm) * CEXP);
                pr[sub][0] = e0; pr[sub][1] = e1; pr[sub][2] = e2; pr[sub][3] = e3;
                rs += (e0 + e1) + (e2 + e3);
            }
            rs += __shfl_xor(rs, 16, 64);
            rs += __shfl_xor(rs, 32, 64);
            ll += rs;
#pragma unroll
            for (int sub = 0; sub < 8; ++sub) {
                uint2 pk;
                pk.x = (unsigned)f2bf(pr[sub][0]) | ((unsigned)f2bf(pr[sub][1]) << 16);
                pk.y = (unsigned)f2bf(pr[sub][2]) | ((unsigned)f2bf(pr[sub][3]) << 16);
                const int wb = (colg * 256 + sub * 32 + rowg * 8) ^ sw;
                *(uint2*)(Pw + wb) = pk;
            }
            bf16x8 pf[4];
#pragma unroll
            for (int kc = 0; kc < 4; ++kc)
                pf[kc] = *(const bf16x8*)(Pw + ((colg * 256 + kc * 64 + rowg * 16) ^ sw));
#pragma unroll
            for (int g = 0; g < 4; ++g) {
                const int vb0 = (g * 16 + colg) * 256 + rowg * 16;
#pragma unroll
                for (int kc = 0; kc < 4; ++kc) {
                    bf16x8 vf = *(const bf16x8*)(Vsb + ((vb0 + kc * 64) ^ sw));
                    O[g] = mfma16(pf[kc], vf, O[g]);
                }
            }
        }
        __syncthreads();
    }

#pragma unroll
    for (int r = 0; r < 4; ++r) {
        const float lr = __shfl(ll, (lane & 48) + rowg * 4 + r, 64);
        const float rc = 1.f / lr;
        const size_t base = (size_t)(b * T + q0 + rowg * 4 + r) * C + h * 64;
#pragma unroll
        for (int g = 0; g < 4; ++g)
            concat[base + g * 16 + colg] = f2bf(O[g][r] * rc);
    }
}

// ---------------------------------------------------------------------------
extern "C" void kernel_launch(void* const* d_in, const int* in_sizes, int n_in,
                              void* d_out, int out_size, void* d_ws, size_t ws_size,
                              hipStream_t stream) {
    const float* q  = (const float*)d_in[0];
    const float* k  = (const float*)d_in[1];
    const float* v  = (const float*)d_in[2];
    const float* Wq = (const float*)d_in[3];
    const float* Wk = (const float*)d_in[4];
    const float* Wv = (const float*)d_in[5];
    const float* Wo = (const float*)d_in[6];
    float* out = (float*)d_out;

    constexpr size_t NELEM = (size_t)4096 * 1024;  // 4M
    constexpr size_t WSZ   = (size_t)1 << 20;      // 1M
    u16* Wbf = (u16*)d_ws;          // bf16 weights    4M
    u16* Qp  = Wbf + 4 * WSZ;       // proj Q          4M
    u16* Kp  = Qp + NELEM;          // proj K          4M
    u16* Vt  = Kp + NELEM;          // proj V (transp) 4M
    u16* Cc  = Vt + NELEM;          // attn concat     4M

    cvtW<<<2048, 256, 0, stream>>>(Wq, Wk, Wv, Wo, Wbf);

    gemm_qkv<<<768, 256, 0, stream>>>(q, k, v, Wbf, Qp, Kp, Vt);

    attn_causal<<<1024, 256, 0, stream>>>(Qp, Kp, Vt, Cc);

    gemm_out<<<512, 256, 0, stream>>>(Cc, Wbf + 3 * WSZ, out);
}

// Round 13
// 132.032 us; speedup vs baseline: 1.4235x; 1.0181x over previous
//
#include <hip/hip_runtime.h>
#include <hip/hip_bf16.h>

typedef __bf16 bf16x8 __attribute__((ext_vector_type(8)));
typedef float  f32x4  __attribute__((ext_vector_type(4)));
typedef unsigned short u16;

__device__ __forceinline__ u16 f2bf(float f) {
    __bf16 h = (__bf16)f;
    return __builtin_bit_cast(u16, h);
}

__device__ __forceinline__ f32x4 mfma16(bf16x8 a, bf16x8 b, f32x4 c) {
    return __builtin_amdgcn_mfma_f32_16x16x32_bf16(a, b, c, 0, 0, 0);
}

__device__ __forceinline__ bf16x8 cvt8(float4 a0, float4 a1) {
    bf16x8 u;
    u[0] = (__bf16)a0.x; u[1] = (__bf16)a0.y; u[2] = (__bf16)a0.z; u[3] = (__bf16)a0.w;
    u[4] = (__bf16)a1.x; u[5] = (__bf16)a1.y; u[6] = (__bf16)a1.z; u[7] = (__bf16)a1.w;
    return u;
}

// ---------------------------------------------------------------------------
// cvtW: Wq,Wk,Wv,Wo (1M elems each) fp32 -> bf16 concatenated.
// ---------------------------------------------------------------------------
__global__ __launch_bounds__(256) void cvtW(const float* __restrict__ W0,
                                            const float* __restrict__ W1,
                                            const float* __restrict__ W2,
                                            const float* __restrict__ W3,
                                            u16* __restrict__ dst) {
    const int t     = blockIdx.x * 256 + threadIdx.x;   // 0..512K-1
    const int which = t >> 17;
    const int off   = (t & 0x1FFFF) * 8;
    const float* s  = (which == 0) ? W0 : (which == 1) ? W1 : (which == 2) ? W2 : W3;
    float4 f0 = *(const float4*)(s + off);
    float4 f1 = *(const float4*)(s + off + 4);
    *(bf16x8*)(dst + ((size_t)which << 20) + off) = cvt8(f0, f1);
}

// ---------------------------------------------------------------------------
// Merged Q/K/V GEMM — r11's exact memory/sync structure (BK=32, swizzled
// single-buffered LDS, quad-contiguous global loads, 2 barriers/step) but
// 8 WAVES per block (512 thr, wave-tile 64x32, acc 4x2): same traffic, same
// staged bytes, double the TLP (24 waves/CU) to hide the serial chain.
// ---------------------------------------------------------------------------
__global__ __launch_bounds__(512, 6) void gemm_qkv(const float* __restrict__ q,
                                                   const float* __restrict__ k,
                                                   const float* __restrict__ v,
                                                   const u16* __restrict__ Wb,
                                                   u16* __restrict__ Qp,
                                                   u16* __restrict__ Kp,
                                                   u16* __restrict__ Vt) {
    constexpr int K = 1024, N = 1024;
    __shared__ __align__(16) u16 As[4096];   // 8 KB
    __shared__ __align__(16) u16 Bs[4096];   // 8 KB

    const int tid  = threadIdx.x;
    const int lane = tid & 63;
    const int w    = tid >> 6;          // 0..7
    const int wr = w >> 2, wc = w & 3;  // 2M x 4N wave grid
    const int wg    = (blockIdx.x & 7) * 96 + (blockIdx.x >> 3);  // XCD swizzle
    const int which = wg >> 8;
    const int inner = wg & 255;
    const int m0 = (inner >> 3) * 128, n0 = (inner & 7) * 128;
    const int colg = lane & 15, rowg = lane >> 4;

    const float* A = (which == 0) ? q : (which == 1) ? k : v;
    const u16*   W = Wb + ((size_t)which << 20);

    // staging: one chunk per thread. c=tid: row=c>>2, kc=c&3 (quad-contig)
    const int rowS = tid >> 2, kcS = tid & 3;
    const size_t aoff = (size_t)(m0 + rowS) * K + kcS * 8;   // floats
    const size_t boff = (size_t)(n0 + rowS) * K + kcS * 8;   // u16s
    const int wio = rowS * 32 + (kcS ^ ((rowS >> 1) & 3)) * 8;

    // fragment read offset: row=colg(+16*frag), kc=rowg swizzled
    const int kcr   = rowg ^ ((colg >> 1) & 3);
    const int rbase = colg * 32 + kcr * 8;

    f32x4 acc[4][2];
#pragma unroll
    for (int i = 0; i < 4; ++i)
#pragma unroll
        for (int j = 0; j < 2; ++j) acc[i][j] = (f32x4){0.f, 0.f, 0.f, 0.f};

    for (int t = 0; t < 32; ++t) {
        const int kk = t * 32;
        float4 a0 = *(const float4*)(A + aoff + kk);
        float4 a1 = *(const float4*)(A + aoff + kk + 4);
        uint4  bv = *(const uint4*)(W + boff + kk);
        *(bf16x8*)(&As[wio]) = cvt8(a0, a1);
        *(uint4*)(&Bs[wio]) = bv;
        __syncthreads();

        bf16x8 af[4], bfr[2];
#pragma unroll
        for (int mi = 0; mi < 4; ++mi)
            af[mi] = *(const bf16x8*)(&As[(wr * 64 + mi * 16) * 32 + rbase]);
#pragma unroll
        for (int ni = 0; ni < 2; ++ni)
            bfr[ni] = *(const bf16x8*)(&Bs[(wc * 32 + ni * 16) * 32 + rbase]);
#pragma unroll
        for (int mi = 0; mi < 4; ++mi)
#pragma unroll
            for (int ni = 0; ni < 2; ++ni)
                acc[mi][ni] = mfma16(af[mi], bfr[ni], acc[mi][ni]);
        __syncthreads();
    }

    u16* Crm = (which == 0) ? Qp : Kp;
#pragma unroll
    for (int mi = 0; mi < 4; ++mi) {
#pragma unroll
        for (int ni = 0; ni < 2; ++ni) {
#pragma unroll
            for (int r = 0; r < 4; ++r) {
                const int row = m0 + wr * 64 + mi * 16 + rowg * 4 + r;
                const int col = n0 + wc * 32 + ni * 16 + colg;
                const float vv = acc[mi][ni][r];
                if (which < 2) {
                    Crm[(size_t)row * N + col] = f2bf(vv);
                } else {
                    const int b = row >> 11, tt = row & 2047;
                    const int h = col >> 6,  d = col & 63;
                    Vt[((size_t)((b * 16 + h) * 64 + d) << 11) + tt] = f2bf(vv);
                }
            }
        }
    }
}

// ---------------------------------------------------------------------------
// Output GEMM — r12 version (64x128 tile, 512 blocks, bf16 reg-staged,
// swizzled LDS, 2-phase dbuf pipeline). fp32 out.
// ---------------------------------------------------------------------------
__global__ __launch_bounds__(256) void gemm_out(const u16* __restrict__ Ap,
                                                const u16* __restrict__ W,
                                                float* __restrict__ Cp) {
    constexpr int K = 1024, N = 1024;
    __shared__ __align__(16) u16 As[2][2048];    // 2 x 4 KB
    __shared__ __align__(16) u16 Bs[2][4096];    // 2 x 8 KB

    const int tid  = threadIdx.x;
    const int lane = tid & 63;
    const int w    = tid >> 6;
    const int wr = w >> 1, wc = w & 1;
    const int wg = (blockIdx.x & 7) * 64 + (blockIdx.x >> 3);  // XCD swizzle
    const int m0 = (wg >> 3) * 64, n0 = (wg & 7) * 128;
    const int colg = lane & 15, rowg = lane >> 4;

    const int rowA = tid >> 2, kcA = tid & 3;
    const size_t aoff = (size_t)(m0 + rowA) * K + kcA * 8;
    const int wiA = rowA * 32 + (kcA ^ ((rowA >> 1) & 3)) * 8;

    size_t boff[2];
    int wiB[2];
#pragma unroll
    for (int i = 0; i < 2; ++i) {
        const int c   = i * 256 + tid;
        const int row = c >> 2;
        const int kc  = c & 3;
        boff[i] = (size_t)(n0 + row) * K + kc * 8;
        wiB[i] = row * 32 + (kc ^ ((row >> 1) & 3)) * 8;
    }
    const int kcr   = rowg ^ ((colg >> 1) & 3);
    const int rbase = colg * 32 + kcr * 8;

    f32x4 acc[2][4];
#pragma unroll
    for (int i = 0; i < 2; ++i)
#pragma unroll
        for (int j = 0; j < 4; ++j) acc[i][j] = (f32x4){0.f, 0.f, 0.f, 0.f};

    // prologue
    uint4 av = *(const uint4*)(Ap + aoff);
    uint4 bv[2];
#pragma unroll
    for (int i = 0; i < 2; ++i) bv[i] = *(const uint4*)(W + boff[i]);
    *(uint4*)(&As[0][wiA]) = av;
#pragma unroll
    for (int i = 0; i < 2; ++i) *(uint4*)(&Bs[0][wiB[i]]) = bv[i];
    __syncthreads();

    int p = 0;
    for (int t = 0; t < 32; ++t) {
        if (t < 31) {
            const int kk = (t + 1) * 32;
            av = *(const uint4*)(Ap + aoff + kk);
#pragma unroll
            for (int i = 0; i < 2; ++i) bv[i] = *(const uint4*)(W + boff[i] + kk);
        }
        {
            bf16x8 af[2], bfr[4];
#pragma unroll
            for (int mi = 0; mi < 2; ++mi)
                af[mi] = *(const bf16x8*)(&As[p][(wr * 32 + mi * 16) * 32 + rbase]);
#pragma unroll
            for (int ni = 0; ni < 4; ++ni)
                bfr[ni] = *(const bf16x8*)(&Bs[p][(wc * 64 + ni * 16) * 32 + rbase]);
#pragma unroll
            for (int mi = 0; mi < 2; ++mi)
#pragma unroll
                for (int ni = 0; ni < 4; ++ni)
                    acc[mi][ni] = mfma16(af[mi], bfr[ni], acc[mi][ni]);
        }
        if (t < 31) {
            *(uint4*)(&As[p ^ 1][wiA]) = av;
#pragma unroll
            for (int i = 0; i < 2; ++i) *(uint4*)(&Bs[p ^ 1][wiB[i]]) = bv[i];
        }
        __syncthreads();
        p ^= 1;
    }

#pragma unroll
    for (int mi = 0; mi < 2; ++mi)
#pragma unroll
        for (int ni = 0; ni < 4; ++ni)
#pragma unroll
            for (int r = 0; r < 4; ++r) {
                const int row = m0 + wr * 32 + mi * 16 + rowg * 4 + r;
                const int col = n0 + wc * 64 + ni * 16 + colg;
                Cp[(size_t)row * N + col] = acc[mi][ni][r];
            }
}

// ---------------------------------------------------------------------------
// Flash attention v3 (unchanged): 4-wave blocks, block-staged K/V in swizzled
// LDS, swapped QK^T (lane-local softmax), defer-rescale.
// ---------------------------------------------------------------------------
constexpr float CEXP = 0.18033688011112042f;  // 0.125 * log2(e)

__global__ __launch_bounds__(256) void attn_causal(const u16* __restrict__ Qp,
                                                   const u16* __restrict__ Kp,
                                                   const u16* __restrict__ Vt,
                                                   u16* __restrict__ concat) {
    constexpr int T = 2048, C = 1024;
    __shared__ __align__(16) u16 Ks[128 * 64];
    __shared__ __align__(16) u16 Vs[64 * 128];
    __shared__ __align__(16) u16 Pl[4][2048];

    const int tid  = threadIdx.x;
    const int lane = tid & 63;
    const int w    = tid >> 6;
    const int colg = lane & 15, rowg = lane >> 4;

    const int idx = blockIdx.x;
    const int xcd = idx & 7;
    const int i1  = idx >> 3;
    const int bh  = xcd * 4 + (i1 & 3);
    const int qg  = 31 - (i1 >> 2);
    const int b = bh >> 4, h = bh & 15;

    const int q0 = (qg * 4 + w) * 16;
    const int nt    = (q0 + 143) >> 7;
    const int ktmax = ((qg * 4 + 3) * 16 + 143) >> 7;

    const char* Kg = (const char*)(Kp + (size_t)(b * T) * C + h * 64);
    const char* Vg = (const char*)(Vt + ((size_t)(b * 16 + h) * 64) * T);
    char* Ksb = (char*)Ks;
    char* Vsb = (char*)Vs;
    char* Pw  = (char*)&Pl[w][0];

    const u16* Qb = Qp + (size_t)(b * T + q0 + colg) * C + h * 64;
    const bf16x8 qf0 = *(const bf16x8*)(Qb + rowg * 8);
    const bf16x8 qf1 = *(const bf16x8*)(Qb + 32 + rowg * 8);

    float mm = -1e30f, ll = 0.f;
    f32x4 O[4];
#pragma unroll
    for (int g = 0; g < 4; ++g) O[g] = (f32x4){0.f, 0.f, 0.f, 0.f};

    const int sw = (colg & 7) << 4;

    for (int kt = 0; kt < ktmax; ++kt) {
        const int kvb = kt * 128;
        uint4 kst[4], vst[4];
#pragma unroll
        for (int i2 = 0; i2 < 4; ++i2) {
            const int s  = i2 * 4096 + tid * 16;
            const int kv = s >> 7, ir = s & 127;
            kst[i2] = *(const uint4*)(Kg + (size_t)(kvb + kv) * 2048 + ir);
            const int d = s >> 8, irv = s & 255;
            vst[i2] = *(const uint4*)(Vg + (size_t)d * 4096 + (size_t)kvb * 2 + irv);
        }
#pragma unroll
        for (int i2 = 0; i2 < 4; ++i2) {
            const int s  = i2 * 4096 + tid * 16;
            const int kv = s >> 7;
            *(uint4*)(Ksb + (s ^ ((kv & 7) << 4))) = kst[i2];
            const int d = s >> 8;
            *(uint4*)(Vsb + (s ^ ((d & 7) << 4))) = vst[i2];
        }
        __syncthreads();

        if (kt < nt) {
            float pr[8][4];
#pragma unroll
            for (int sub = 0; sub < 8; ++sub) {
                const int kb = (sub * 16 + colg) * 128 + rowg * 16;
                bf16x8 kf0 = *(const bf16x8*)(Ksb + (kb ^ sw));
                bf16x8 kf1 = *(const bf16x8*)(Ksb + ((kb + 64) ^ sw));
                f32x4 t = (f32x4){0.f, 0.f, 0.f, 0.f};
                t = mfma16(kf0, qf0, t);
                t = mfma16(kf1, qf1, t);
#pragma unroll
                for (int r = 0; r < 4; ++r) pr[sub][r] = t[r];
            }
            if (kvb + 127 > q0) {
#pragma unroll
                for (int sub = 0; sub < 8; ++sub)
#pragma unroll
                    for (int r = 0; r < 4; ++r)
                        if (kvb + sub * 16 + rowg * 4 + r > q0 + colg) pr[sub][r] = -1e30f;
            }
            float mx[8];
#pragma unroll
            for (int sub = 0; sub < 8; ++sub)
                mx[sub] = fmaxf(fmaxf(pr[sub][0], pr[sub][1]), fmaxf(pr[sub][2], pr[sub][3]));
            float pm = fmaxf(fmaxf(fmaxf(mx[0], mx[1]), fmaxf(mx[2], mx[3])),
                             fmaxf(fmaxf(mx[4], mx[5]), fmaxf(mx[6], mx[7])));
            pm = fmaxf(pm, __shfl_xor(pm, 16, 64));
            pm = fmaxf(pm, __shfl_xor(pm, 32, 64));
            if (__any(pm > mm + 40.f)) {
                const float mn = fmaxf(mm, pm);
                const float sc = __builtin_amdgcn_exp2f((mm - mn) * CEXP);
                mm = mn;
                ll *= sc;
#pragma unroll
                for (int r = 0; r < 4; ++r) {
                    const float scr = __shfl(sc, (lane & 48) + rowg * 4 + r, 64);
#pragma unroll
                    for (int g = 0; g < 4; ++g) O[g][r] *= scr;
                }
            }
            float rs = 0.f;
#pragma unroll
            for (int sub = 0; sub < 8; ++sub) {
                const float e0 = __builtin_amdgcn_exp2f((pr[sub][0] - mm) * CEXP);
                const float e1 = __builtin_amdgcn_exp2f((pr[sub][1] - mm) * CEXP);
                const float e2 = __builtin_amdgcn_exp2f((pr[sub][2] - mm) * CEXP);
                const float e3 = __builtin_amdgcn_exp2f((pr[sub][3] - mm) * CEXP);
                pr[sub][0] = e0; pr[sub][1] = e1; pr[sub][2] = e2; pr[sub][3] = e3;
                rs += (e0 + e1) + (e2 + e3);
            }
            rs += __shfl_xor(rs, 16, 64);
            rs += __shfl_xor(rs, 32, 64);
            ll += rs;
#pragma unroll
            for (int sub = 0; sub < 8; ++sub) {
                uint2 pk;
                pk.x = (unsigned)f2bf(pr[sub][0]) | ((unsigned)f2bf(pr[sub][1]) << 16);
                pk.y = (unsigned)f2bf(pr[sub][2]) | ((unsigned)f2bf(pr[sub][3]) << 16);
                const int wb = (colg * 256 + sub * 32 + rowg * 8) ^ sw;
                *(uint2*)(Pw + wb) = pk;
            }
            bf16x8 pf[4];
#pragma unroll
            for (int kc = 0; kc < 4; ++kc)
                pf[kc] = *(const bf16x8*)(Pw + ((colg * 256 + kc * 64 + rowg * 16) ^ sw));
#pragma unroll
            for (int g = 0; g < 4; ++g) {
                const int vb0 = (g * 16 + colg) * 256 + rowg * 16;
#pragma unroll
                for (int kc = 0; kc < 4; ++kc) {
                    bf16x8 vf = *(const bf16x8*)(Vsb + ((vb0 + kc * 64) ^ sw));
                    O[g] = mfma16(pf[kc], vf, O[g]);
                }
            }
        }
        __syncthreads();
    }

#pragma unroll
    for (int r = 0; r < 4; ++r) {
        const float lr = __shfl(ll, (lane & 48) + rowg * 4 + r, 64);
        const float rc = 1.f / lr;
        const size_t base = (size_t)(b * T + q0 + rowg * 4 + r) * C + h * 64;
#pragma unroll
        for (int g = 0; g < 4; ++g)
            concat[base + g * 16 + colg] = f2bf(O[g][r] * rc);
    }
}

// ---------------------------------------------------------------------------
extern "C" void kernel_launch(void* const* d_in, const int* in_sizes, int n_in,
                              void* d_out, int out_size, void* d_ws, size_t ws_size,
                              hipStream_t stream) {
    const float* q  = (const float*)d_in[0];
    const float* k  = (const float*)d_in[1];
    const float* v  = (const float*)d_in[2];
    const float* Wq = (const float*)d_in[3];
    const float* Wk = (const float*)d_in[4];
    const float* Wv = (const float*)d_in[5];
    const float* Wo = (const float*)d_in[6];
    float* out = (float*)d_out;

    constexpr size_t NELEM = (size_t)4096 * 1024;  // 4M
    constexpr size_t WSZ   = (size_t)1 << 20;      // 1M
    u16* Wbf = (u16*)d_ws;          // bf16 weights    4M
    u16* Qp  = Wbf + 4 * WSZ;       // proj Q          4M
    u16* Kp  = Qp + NELEM;          // proj K          4M
    u16* Vt  = Kp + NELEM;          // proj V (transp) 4M
    u16* Cc  = Vt + NELEM;          // attn concat     4M

    cvtW<<<2048, 256, 0, stream>>>(Wq, Wk, Wv, Wo, Wbf);

    gemm_qkv<<<768, 512, 0, stream>>>(q, k, v, Wbf, Qp, Kp, Vt);

    attn_causal<<<1024, 256, 0, stream>>>(Qp, Kp, Vt, Cc);

    gemm_out<<<512, 256, 0, stream>>>(Cc, Wbf + 3 * WSZ, out);
}